// Round 11
// baseline (1683.866 us; speedup 1.0000x reference)
//
#include <hip/hip_runtime.h>
#include <hip/hip_bf16.h>
#include <math.h>

#define V_   32000
#define D_   512
#define L_   6
#define H_   8
#define DH_  64
#define DFF_ 2048
#define B_   8
#define T_   1024
#define BT_  (B_*T_)

typedef __attribute__((ext_vector_type(4))) float f32x4;
typedef __attribute__((ext_vector_type(8))) short short8;
using bf16_t = __hip_bfloat16;

__device__ __forceinline__ float b2f(unsigned short u) {
    union { unsigned int i; float f; } v; v.i = ((unsigned int)u) << 16; return v.f;
}
__device__ __forceinline__ unsigned short f2b(float f) {
    bf16_t h = __float2bfloat16(f);
    return *reinterpret_cast<unsigned short*>(&h);
}
__device__ __forceinline__ void gl16(const void* g, void* l) {
    __builtin_amdgcn_global_load_lds((const __attribute__((address_space(1))) void*)g,
                                     (__attribute__((address_space(3))) void*)l, 16, 0, 0);
}
__device__ __forceinline__ float gelu_exact(float v) {
    return 0.5f * v * (1.0f + erff(v * 0.70710678118654752f));
}

// -------- fused embedding + LN1(layer0): x = wte[idx]+wpe, h = LN(x) -------
__global__ __launch_bounds__(128) void embed_ln_kernel(
        const int* __restrict__ idx, const float* __restrict__ wte,
        const float* __restrict__ wpe, const float* __restrict__ g,
        const float* __restrict__ bb, float* __restrict__ x,
        bf16_t* __restrict__ hout) {
    int bt = blockIdx.x;
    int tt = bt & (T_ - 1);
    int tok = idx[bt];
    int i = threadIdx.x;
    float4 a = ((const float4*)(wte + (size_t)tok * D_))[i];
    float4 p = ((const float4*)(wpe + (size_t)tt * D_))[i];
    float4 v = make_float4(a.x + p.x, a.y + p.y, a.z + p.z, a.w + p.w);
    ((float4*)(x + (size_t)bt * D_))[i] = v;

    float s  = v.x + v.y + v.z + v.w;
    float sq = v.x*v.x + v.y*v.y + v.z*v.z + v.w*v.w;
    #pragma unroll
    for (int o = 32; o > 0; o >>= 1) {
        s  += __shfl_down(s,  o);
        sq += __shfl_down(sq, o);
    }
    __shared__ float ss[2], ssq[2];
    if ((i & 63) == 0) { ss[i >> 6] = s; ssq[i >> 6] = sq; }
    __syncthreads();
    float mean = (ss[0] + ss[1]) * (1.0f / D_);
    float var  = (ssq[0] + ssq[1]) * (1.0f / D_) - mean * mean;
    float rstd = rsqrtf(var + 1e-5f);
    float4 gg = ((const float4*)g)[i];
    float4 b2 = ((const float4*)bb)[i];
    ushort4 o4;
    o4.x = f2b((v.x - mean) * rstd * gg.x + b2.x);
    o4.y = f2b((v.y - mean) * rstd * gg.y + b2.y);
    o4.z = f2b((v.z - mean) * rstd * gg.z + b2.z);
    o4.w = f2b((v.w - mean) * rstd * gg.w + b2.w);
    ((ushort4*)(hout + (size_t)bt * D_))[i] = o4;
}

// ---------------- fp32 -> bf16 convert (no transpose) ----------------
__global__ __launch_bounds__(256) void conv_kernel(
        const float* __restrict__ s, bf16_t* __restrict__ d, int n4) {
    int i = blockIdx.x * 256 + threadIdx.x;
    if (i >= n4) return;
    float4 f = ((const float4*)s)[i];
    ushort4 u = make_ushort4(f2b(f.x), f2b(f.y), f2b(f.z), f2b(f.w));
    ((ushort4*)d)[i] = u;
}

// ------------- fp32 [K][N] -> bf16 [N][K] transpose-convert, z = layer -----
__global__ __launch_bounds__(256) void tconv_kernel(
        const float* __restrict__ src, bf16_t* __restrict__ dst, int K, int N) {
    size_t ls = (size_t)K * N;
    const float* s = src + blockIdx.z * ls;
    bf16_t* d = dst + blockIdx.z * ls;
    __shared__ float tile[32][33];
    int n0 = blockIdx.x * 32, k0 = blockIdx.y * 32;
    int c = threadIdx.x & 31, r8 = threadIdx.x >> 5;
    #pragma unroll
    for (int i = 0; i < 4; ++i) {
        int r = r8 + i * 8;
        tile[r][c] = s[(size_t)(k0 + r) * N + n0 + c];
    }
    __syncthreads();
    #pragma unroll
    for (int i = 0; i < 4; ++i) {
        int r = r8 + i * 8;
        d[(size_t)(n0 + r) * K + k0 + c] = __float2bfloat16(tile[c][r]);
    }
}

// ----- V transpose: qkvb [BT][3D] V-part -> vt [(b*H+h)*DH + d][T] bf16 ----
__global__ __launch_bounds__(256) void vtrans_kernel(
        const bf16_t* __restrict__ qkv, bf16_t* __restrict__ vt) {
    const unsigned short* q = (const unsigned short*)qkv;
    unsigned short* d = (unsigned short*)vt;
    __shared__ unsigned short tile[32][33];
    int bh = blockIdx.z;                 // b*8+h
    int b  = bh >> 3, h = bh & 7;
    int t0 = blockIdx.x * 32, d0 = blockIdx.y * 32;
    int c = threadIdx.x & 31, r8 = threadIdx.x >> 5;
    #pragma unroll
    for (int i = 0; i < 4; ++i) {
        int r = r8 + i * 8;   // t index in tile
        tile[r][c] = q[(size_t)(b * T_ + t0 + r) * (3 * D_) + 2 * D_ + h * DH_ + d0 + c];
    }
    __syncthreads();
    #pragma unroll
    for (int i = 0; i < 4; ++i) {
        int r = r8 + i * 8;   // d index in tile
        d[(size_t)(bh * DH_ + d0 + r) * T_ + t0 + c] = tile[c][r];
    }
}

// ------------- bf16 MFMA GEMM (128x128, templated BK, swizzled) -----------
// 32KB LDS at BK=64 -> ~4 blocks/CU: inter-block overlap hides the
// per-block prologue latency + epilogue write (short-K regime).
template<int BK, int ACT, bool OBF, bool RES, bool CONVB>
__global__ __launch_bounds__(256) void mm_kernel(
        const bf16_t* __restrict__ A,
        const bf16_t* __restrict__ Bt,
        const float*  __restrict__ Bf,
        const float*  __restrict__ bias,
        const float*  __restrict__ res,
        void* __restrict__ Cout,
        int M, int N, int K)
{
    constexpr int SLOTS = BK / 8;
    constexpr int CH    = BK / 16;
    __shared__ __align__(16) unsigned short As[128 * BK];
    __shared__ __align__(16) unsigned short Bs[128 * BK];
    const int nwg = gridDim.x;
    const int orig = blockIdx.x;
    const int q8 = nwg >> 3, r8 = nwg & 7;
    const int xcd = orig & 7, lin = orig >> 3;
    const int wg = (xcd < r8) ? xcd * (q8 + 1) + lin
                              : r8 * (q8 + 1) + (xcd - r8) * q8 + lin;
    const int gym = M >> 7;
    const int by = wg % gym;
    const int bx = wg / gym;

    const int t    = threadIdx.x;
    const int row0 = by * 128;
    const int col0 = bx * 128;
    const int lane = t & 63;
    const int wid  = t >> 6;
    const int wm   = (wid & 1) * 64;
    const int wn   = (wid >> 1) * 64;
    const int fr   = lane & 15;
    const int fq   = lane >> 4;

    f32x4 acc[4][4];
    #pragma unroll
    for (int m = 0; m < 4; ++m)
        #pragma unroll
        for (int n = 0; n < 4; ++n)
            acc[m][n] = (f32x4)(0.0f);

    const unsigned short* Ab  = (const unsigned short*)A;
    const unsigned short* Btb = (const unsigned short*)Bt;

    for (int k0 = 0; k0 < K; k0 += BK) {
        __syncthreads();
        #pragma unroll
        for (int i = 0; i < CH; ++i) {
            int c = t + i * 256;
            int row = c / SLOTS;
            int sl  = (c & (SLOTS - 1)) ^ (row & 7);
            gl16(Ab + (size_t)(row0 + row) * K + k0 + sl * 8, As + (size_t)c * 8);
        }
        if (!CONVB) {
            #pragma unroll
            for (int i = 0; i < CH; ++i) {
                int c = t + i * 256;
                int row = c / SLOTS;
                int sl  = (c & (SLOTS - 1)) ^ (row & 7);
                gl16(Btb + (size_t)(col0 + row) * K + k0 + sl * 8, Bs + (size_t)c * 8);
            }
        } else {
            #pragma unroll
            for (int i = 0; i < CH; ++i) {
                int c = t + i * 256;
                int row = c / SLOTS;
                int sl  = (c & (SLOTS - 1)) ^ (row & 7);
                const float* sp = Bf + (size_t)(col0 + row) * K + k0 + sl * 8;
                float4 f0 = ((const float4*)sp)[0];
                float4 f1 = ((const float4*)sp)[1];
                short8 pk;
                pk[0] = f2b(f0.x); pk[1] = f2b(f0.y); pk[2] = f2b(f0.z); pk[3] = f2b(f0.w);
                pk[4] = f2b(f1.x); pk[5] = f2b(f1.y); pk[6] = f2b(f1.z); pk[7] = f2b(f1.w);
                *(short8*)(Bs + (size_t)c * 8) = pk;
            }
        }
        __syncthreads();

        #pragma unroll
        for (int kk = 0; kk < BK / 32; ++kk) {
            short8 av[4], bv[4];
            #pragma unroll
            for (int m = 0; m < 4; ++m) {
                int R = wm + m * 16 + fr;
                int sl = (kk * 4 + fq) ^ (fr & 7);
                av[m] = *(const short8*)(As + (size_t)R * BK + sl * 8);
            }
            #pragma unroll
            for (int n = 0; n < 4; ++n) {
                int R = wn + n * 16 + fr;
                int sl = (kk * 4 + fq) ^ (fr & 7);
                bv[n] = *(const short8*)(Bs + (size_t)R * BK + sl * 8);
            }
            #pragma unroll
            for (int m = 0; m < 4; ++m)
                #pragma unroll
                for (int n = 0; n < 4; ++n)
                    acc[m][n] = __builtin_amdgcn_mfma_f32_16x16x32_bf16(av[m], bv[n], acc[m][n], 0, 0, 0);
        }
    }

    #pragma unroll
    for (int n = 0; n < 4; ++n) {
        int col = col0 + wn + n * 16 + fr;
        float bb = bias ? bias[col] : 0.0f;
        #pragma unroll
        for (int m = 0; m < 4; ++m) {
            int rbase = row0 + wm + m * 16 + fq * 4;
            #pragma unroll
            for (int r = 0; r < 4; ++r) {
                float v = acc[m][n][r] + bb;
                if (ACT == 1) v = gelu_exact(v);
                size_t off = (size_t)(rbase + r) * N + col;
                if (RES) v += res[off];
                if (OBF) ((bf16_t*)Cout)[off] = __float2bfloat16(v);
                else     ((float*)Cout)[off]  = v;
            }
        }
    }
}

// ====== fused GEMM(32x512 tile) + bias + residual + LayerNorm (r8 v1) ======
__global__ __launch_bounds__(512) void mm_ln_kernel(
        const bf16_t* __restrict__ A,
        const bf16_t* __restrict__ Bt,     // [512][K]
        const float*  __restrict__ bias,   // [512]
        float*        __restrict__ xio,    // [M][512] residual in/out
        const float*  __restrict__ g,
        const float*  __restrict__ lb,
        bf16_t*       __restrict__ hout,   // [M][512]
        int M, int K)
{
    __shared__ __align__(16) unsigned short As[32 * 64];    // 4 KB
    __shared__ __align__(16) unsigned short Bs[512 * 64];   // 64 KB
    __shared__ float stats[32][8][2];                       // 2 KB

    const int row0 = blockIdx.x * 32;
    const int t    = threadIdx.x;
    const int lane = t & 63;
    const int w    = t >> 6;
    const int fr   = lane & 15;
    const int fq   = lane >> 4;

    const unsigned short* Ab  = (const unsigned short*)A;
    const unsigned short* Btb = (const unsigned short*)Bt;

    f32x4 acc[2][4];
    #pragma unroll
    for (int m = 0; m < 2; ++m)
        #pragma unroll
        for (int n = 0; n < 4; ++n)
            acc[m][n] = (f32x4)(0.0f);

    for (int k0 = 0; k0 < K; k0 += 64) {
        __syncthreads();
        if (t < 256) {              // A: 32 rows x 8 slots
            int c = t;
            int row = c >> 3, sl = (c & 7) ^ (row & 7);
            gl16(Ab + (size_t)(row0 + row) * K + k0 + sl * 8, As + (size_t)c * 8);
        }
        #pragma unroll
        for (int i = 0; i < 8; ++i) {   // B: 512 rows x 8 slots
            int c = t + i * 512;
            int row = c >> 3, sl = (c & 7) ^ (row & 7);
            gl16(Btb + (size_t)row * K + k0 + sl * 8, Bs + (size_t)c * 8);
        }
        __syncthreads();

        #pragma unroll
        for (int kk = 0; kk < 2; ++kk) {
            int sl = (kk * 4 + fq) ^ (fr & 7);
            short8 av[2], bv[4];
            #pragma unroll
            for (int m = 0; m < 2; ++m)
                av[m] = *(const short8*)(As + (size_t)(m * 16 + fr) * 64 + sl * 8);
            #pragma unroll
            for (int n = 0; n < 4; ++n)
                bv[n] = *(const short8*)(Bs + (size_t)(w * 64 + n * 16 + fr) * 64 + sl * 8);
            #pragma unroll
            for (int m = 0; m < 2; ++m)
                #pragma unroll
                for (int n = 0; n < 4; ++n)
                    acc[m][n] = __builtin_amdgcn_mfma_f32_16x16x32_bf16(av[m], bv[n], acc[m][n], 0, 0, 0);
        }
    }

    float vv[2][4][4];
    #pragma unroll
    for (int m = 0; m < 2; ++m) {
        #pragma unroll
        for (int r = 0; r < 4; ++r) {
            int rowl = m * 16 + fq * 4 + r;
            float ps = 0.0f, pq = 0.0f;
            #pragma unroll
            for (int n = 0; n < 4; ++n) {
                int col = w * 64 + n * 16 + fr;
                float v = acc[m][n][r] + bias[col] +
                          xio[(size_t)(row0 + rowl) * D_ + col];
                vv[m][n][r] = v;
                ps += v; pq += v * v;
            }
            ps += __shfl_xor(ps, 1); pq += __shfl_xor(pq, 1);
            ps += __shfl_xor(ps, 2); pq += __shfl_xor(pq, 2);
            ps += __shfl_xor(ps, 4); pq += __shfl_xor(pq, 4);
            ps += __shfl_xor(ps, 8); pq += __shfl_xor(pq, 8);
            if (fr == 0) { stats[rowl][w][0] = ps; stats[rowl][w][1] = pq; }
        }
    }
    __syncthreads();

    #pragma unroll
    for (int m = 0; m < 2; ++m) {
        #pragma unroll
        for (int r = 0; r < 4; ++r) {
            int rowl = m * 16 + fq * 4 + r;
            float su = 0.0f, sq = 0.0f;
            #pragma unroll
            for (int ww = 0; ww < 8; ++ww) {
                su += stats[rowl][ww][0];
                sq += stats[rowl][ww][1];
            }
            float mean = su * (1.0f / D_);
            float var  = sq * (1.0f / D_) - mean * mean;
            float rstd = rsqrtf(var + 1e-5f);
            #pragma unroll
            for (int n = 0; n < 4; ++n) {
                int col = w * 64 + n * 16 + fr;
                float v = vv[m][n][r];
                size_t off = (size_t)(row0 + rowl) * D_ + col;
                xio[off] = v;
                hout[off] = __float2bfloat16((v - mean) * rstd * g[col] + lb[col]);
            }
        }
    }
}

// ============ 256x256 8-phase pipelined bf16 GEMM (T2+T3+T4+T5) ============
#define MM8_PHASE(MH, NH, HALF, SRCB, R0, DSTB)                               \
  {                                                                           \
    short8 af[2][4]; short8 bg[2][2];                                         \
    _Pragma("unroll")                                                         \
    for (int ks = 0; ks < 2; ++ks) {                                          \
      _Pragma("unroll")                                                       \
      for (int m = 0; m < 4; ++m) {                                           \
        int row = ((MH)*4 + m)*32 + wm*16 + fr;                               \
        int sl  = (ks*4 + fq) ^ (fr & 7);                                     \
        af[ks][m] = *(const short8*)(curA + (size_t)row*64 + (size_t)sl*8);   \
      }                                                                       \
      _Pragma("unroll")                                                       \
      for (int n = 0; n < 2; ++n) {                                           \
        int col = ((NH)*2 + n)*64 + wn*16 + fr;                               \
        int sl  = (ks*4 + fq) ^ (fr & 7);                                     \
        bg[ks][n] = *(const short8*)(curB + (size_t)col*64 + (size_t)sl*8);   \
      }                                                                       \
    }                                                                         \
    if (pf) {                                                                 \
      _Pragma("unroll")                                                       \
      for (int i = 0; i < 2; ++i) {                                           \
        int c = (HALF)*1024 + i*512 + t;                                      \
        int row = c >> 3, sl = (c & 7) ^ (row & 7);                           \
        gl16(SRCB + (size_t)((R0) + row)*K + k0n + sl*8,                      \
             DSTB + (size_t)c*8);                                             \
      }                                                                       \
      asm volatile("s_waitcnt vmcnt(2)" ::: "memory");                        \
    } else if ((MH) == 0 && (NH) == 0) {                                      \
      asm volatile("s_waitcnt vmcnt(0)" ::: "memory");                        \
    }                                                                         \
    asm volatile("s_barrier" ::: "memory");                                   \
    asm volatile("s_waitcnt lgkmcnt(0)" ::: "memory");                        \
    __builtin_amdgcn_sched_barrier(0);                                        \
    __builtin_amdgcn_s_setprio(1);                                            \
    _Pragma("unroll")                                                         \
    for (int ks = 0; ks < 2; ++ks)                                            \
      _Pragma("unroll")                                                       \
      for (int m = 0; m < 4; ++m)                                             \
        _Pragma("unroll")                                                     \
        for (int n = 0; n < 2; ++n)                                           \
          acc[(MH)*4+m][(NH)*2+n] = __builtin_amdgcn_mfma_f32_16x16x32_bf16(  \
              af[ks][m], bg[ks][n], acc[(MH)*4+m][(NH)*2+n], 0, 0, 0);        \
    __builtin_amdgcn_s_setprio(0);                                            \
    __builtin_amdgcn_sched_barrier(0);                                        \
    asm volatile("s_barrier" ::: "memory");                                   \
  }

template<int ACT, bool OBF>
__global__ __launch_bounds__(512) void mm8_kernel(
        const bf16_t* __restrict__ A,    // [M][K] bf16
        const bf16_t* __restrict__ Bt,   // [N][K] bf16
        const float*  __restrict__ bias,
        void* __restrict__ Cout,
        int M, int N, int K)
{
    __shared__ __align__(16) unsigned short sA[2][256 * 64];
    __shared__ __align__(16) unsigned short sB[2][256 * 64];

    const int nwg = gridDim.x;
    const int orig = blockIdx.x;
    const int q8 = nwg >> 3, r8 = nwg & 7;
    const int xcd = orig & 7, lin = orig >> 3;
    const int wg = (xcd < r8) ? xcd * (q8 + 1) + lin
                              : r8 * (q8 + 1) + (xcd - r8) * q8 + lin;
    const int gym = M >> 8;
    const int by = wg % gym;
    const int bx = wg / gym;
    const int row0 = by * 256;
    const int col0 = bx * 256;

    const int t    = threadIdx.x;
    const int lane = t & 63;
    const int wid  = t >> 6;
    const int wm   = wid >> 2;
    const int wn   = wid & 3;
    const int fr   = lane & 15;
    const int fq   = lane >> 4;

    const unsigned short* Ab = (const unsigned short*)A;
    const unsigned short* Bb = (const unsigned short*)Bt;

    f32x4 acc[8][4];
    #pragma unroll
    for (int m = 0; m < 8; ++m)
        #pragma unroll
        for (int n = 0; n < 4; ++n)
            acc[m][n] = (f32x4)(0.0f);

    const int NK = K >> 6;

    #pragma unroll
    for (int h = 0; h < 2; ++h)
        #pragma unroll
        for (int i = 0; i < 2; ++i) {
            int c = h * 1024 + i * 512 + t;
            int row = c >> 3, sl = (c & 7) ^ (row & 7);
            gl16(Ab + (size_t)(row0 + row) * K + sl * 8, &sA[0][(size_t)c * 8]);
            gl16(Bb + (size_t)(col0 + row) * K + sl * 8, &sB[0][(size_t)c * 8]);
        }
    asm volatile("s_waitcnt vmcnt(0)" ::: "memory");
    asm volatile("s_barrier" ::: "memory");

    for (int s = 0; s < NK; ++s) {
        const unsigned short* curA = sA[s & 1];
        const unsigned short* curB = sB[s & 1];
        unsigned short* nxA = (unsigned short*)sA[(s + 1) & 1];
        unsigned short* nxB = (unsigned short*)sB[(s + 1) & 1];
        const int k0n = (s + 1) << 6;
        const bool pf = (s + 1) < NK;
        MM8_PHASE(0, 0, 0, Ab, row0, nxA)
        MM8_PHASE(1, 0, 0, Bb, col0, nxB)
        MM8_PHASE(0, 1, 1, Ab, row0, nxA)
        MM8_PHASE(1, 1, 1, Bb, col0, nxB)
    }

    #pragma unroll
    for (int n = 0; n < 4; ++n) {
        int col = col0 + n * 64 + wn * 16 + fr;
        float bb = bias ? bias[col] : 0.0f;
        #pragma unroll
        for (int m = 0; m < 8; ++m) {
            int rbase = row0 + m * 32 + wm * 16 + fq * 4;
            #pragma unroll
            for (int r = 0; r < 4; ++r) {
                float v = acc[m][n][r] + bb;
                if (ACT == 1) v = gelu_exact(v);
                size_t off = (size_t)(rbase + r) * N + col;
                if (OBF) ((bf16_t*)Cout)[off] = __float2bfloat16(v);
                else     ((float*)Cout)[off]  = v;
            }
        }
    }
}

// ---- MFMA flash attention: gl16-staged K/V (pre-swizzled src), dbuf -------
__global__ __launch_bounds__(512, 2) void flash_kernel(
        const bf16_t* __restrict__ qkv, const bf16_t* __restrict__ vt,
        bf16_t* __restrict__ y)
{
    __shared__ __align__(16) unsigned short Ks[2][64 * 64];  // [j][d] 8KB x2
    __shared__ __align__(16) unsigned short Vs[2][64 * 64];  // [d][j] 8KB x2
    __shared__ __align__(16) unsigned short Pls[128][72];    // 18.4KB

    const int qt = (T_ / 128 - 1) - (blockIdx.x >> 6);
    const int bh = blockIdx.x & 63;
    const int h  = bh & (H_ - 1);
    const int b  = bh >> 3;
    const int t  = threadIdx.x;
    const int lane = t & 63;
    const int w    = t >> 6;
    const int fr   = lane & 15;
    const int fq   = lane >> 4;
    const int srow = t >> 3;                 // staging row (0..63)
    const int ssl  = (t & 7) ^ (srow & 7);   // pre-swizzled source slot

    const unsigned short* qkvb = (const unsigned short*)qkv;
    const unsigned short* vtb  = (const unsigned short*)vt;

    short8 avq[2];
    {
        const unsigned short* qrow = qkvb +
            (size_t)(b * T_ + qt * 128 + w * 16 + fr) * (3 * D_) + h * DH_;
        avq[0] = *(const short8*)(qrow + fq * 8);
        avq[1] = *(const short8*)(qrow + 32 + fq * 8);
    }

    float mi[4], li[4];
    f32x4 oacc[4];
    #pragma unroll
    for (int r = 0; r < 4; ++r) { mi[r] = -INFINITY; li[r] = 0.0f; }
    #pragma unroll
    for (int d = 0; d < 4; ++d) oacc[d] = (f32x4)(0.0f);

    const int nt = 2 * qt + 2;

    gl16(qkvb + (size_t)(b * T_ + srow) * (3 * D_) + D_ + h * DH_ + ssl * 8,
         &Ks[0][(size_t)t * 8]);
    gl16(vtb + (size_t)(bh * DH_ + srow) * T_ + ssl * 8,
         &Vs[0][(size_t)t * 8]);
    __syncthreads();

    for (int jt = 0; jt < nt; ++jt) {
        const int cur = jt & 1;
        if (jt + 1 < nt) {   // async-stage next tile into buf^1
            gl16(qkvb + (size_t)(b * T_ + (jt + 1) * 64 + srow) * (3 * D_)
                     + D_ + h * DH_ + ssl * 8,
                 &Ks[cur ^ 1][(size_t)t * 8]);
            gl16(vtb + (size_t)(bh * DH_ + srow) * T_ + (jt + 1) * 64 + ssl * 8,
                 &Vs[cur ^ 1][(size_t)t * 8]);
        }

        f32x4 s[4];
        #pragma unroll
        for (int jb = 0; jb < 4; ++jb) s[jb] = (f32x4)(0.0f);
        #pragma unroll
        for (int ks = 0; ks < 2; ++ks) {
            int sl = (ks * 4 + fq) ^ (fr & 7);
            #pragma unroll
            for (int jb = 0; jb < 4; ++jb) {
                short8 bv = *(const short8*)(&Ks[cur][(size_t)(jb * 16 + fr) * 64 + sl * 8]);
                s[jb] = __builtin_amdgcn_mfma_f32_16x16x32_bf16(avq[ks], bv, s[jb], 0, 0, 0);
            }
        }

        float sv[4][4];
        const int qgb = qt * 128 + w * 16 + fq * 4;
        #pragma unroll
        for (int jb = 0; jb < 4; ++jb) {
            int jg = jt * 64 + jb * 16 + fr;
            #pragma unroll
            for (int r = 0; r < 4; ++r) {
                float x = s[jb][r] * 0.125f;
                sv[jb][r] = (jg > qgb + r) ? -INFINITY : x;
            }
        }

        #pragma unroll
        for (int r = 0; r < 4; ++r) {
            float tm = fmaxf(fmaxf(sv[0][r], sv[1][r]), fmaxf(sv[2][r], sv[3][r]));
            tm = fmaxf(tm, __shfl_xor(tm, 1));
            tm = fmaxf(tm, __shfl_xor(tm, 2));
            tm = fmaxf(tm, __shfl_xor(tm, 4));
            tm = fmaxf(tm, __shfl_xor(tm, 8));
            float mnew = fmaxf(mi[r], tm);
            float corr = __expf(mi[r] - mnew);
            float tsum = 0.0f;
            #pragma unroll
            for (int jb = 0; jb < 4; ++jb) {
                float p = __expf(sv[jb][r] - mnew);
                sv[jb][r] = p;
                tsum += p;
            }
            tsum += __shfl_xor(tsum, 1);
            tsum += __shfl_xor(tsum, 2);
            tsum += __shfl_xor(tsum, 4);
            tsum += __shfl_xor(tsum, 8);
            li[r] = li[r] * corr + tsum;
            mi[r] = mnew;
            #pragma unroll
            for (int db = 0; db < 4; ++db) oacc[db][r] *= corr;
        }

        #pragma unroll
        for (int jb = 0; jb < 4; ++jb)
            #pragma unroll
            for (int r = 0; r < 4; ++r)
                Pls[w * 16 + fq * 4 + r][jb * 16 + fr] = f2b(sv[jb][r]);

        #pragma unroll
        for (int ks = 0; ks < 2; ++ks) {
            short8 ap = *(const short8*)(&Pls[w * 16 + fr][ks * 32 + fq * 8]);
            int sl = (ks * 4 + fq) ^ (fr & 7);
            #pragma unroll
            for (int db = 0; db < 4; ++db) {
                short8 bv = *(const short8*)(&Vs[cur][(size_t)(db * 16 + fr) * 64 + sl * 8]);
                oacc[db] = __builtin_amdgcn_mfma_f32_16x16x32_bf16(ap, bv, oacc[db], 0, 0, 0);
            }
        }

        __syncthreads();  // implicit vmcnt(0)+lgkmcnt(0): prefetch landed
    }

    unsigned short* yb = (unsigned short*)y;
    #pragma unroll
    for (int r = 0; r < 4; ++r) {
        float inv = 1.0f / li[r];
        size_t row = (size_t)(b * T_ + qt * 128 + w * 16 + fq * 4 + r);
        #pragma unroll
        for (int db = 0; db < 4; ++db)
            yb[row * D_ + h * DH_ + db * 16 + fr] = f2b(oacc[db][r] * inv);
    }
}

// ---------------- launcher ----------------
extern "C" void kernel_launch(void* const* d_in, const int* in_sizes, int n_in,
                              void* d_out, int out_size, void* d_ws, size_t ws_size,
                              hipStream_t stream) {
    const int*   idx   = (const int*)  d_in[0];
    const float* wte   = (const float*)d_in[1];
    const float* wpe   = (const float*)d_in[2];
    const float* ln1_g = (const float*)d_in[3];
    const float* ln1_b = (const float*)d_in[4];
    const float* w_qkv = (const float*)d_in[5];
    const float* b_qkv = (const float*)d_in[6];
    const float* w_ao  = (const float*)d_in[7];
    const float* b_ao  = (const float*)d_in[8];
    const float* ln2_g = (const float*)d_in[9];
    const float* ln2_b = (const float*)d_in[10];
    const float* w_fc  = (const float*)d_in[11];
    const float* b_fc  = (const float*)d_in[12];
    const float* w_pr  = (const float*)d_in[13];
    const float* b_pr  = (const float*)d_in[14];
    const float* lnf_g = (const float*)d_in[15];
    const float* lnf_b = (const float*)d_in[16];
    float* outf = (float*)d_out;

    char* base = (char*)d_out;
    size_t off = 0;
    auto alloc = [&](size_t bytes) {
        void* p = base + off;
        off += (bytes + 255) & ~(size_t)255;
        return p;
    };
    bf16_t* wqkvT = (bf16_t*)alloc((size_t)L_ * 3 * D_ * D_ * 2);
    bf16_t* waoT  = (bf16_t*)alloc((size_t)L_ * D_ * D_ * 2);
    bf16_t* wfcT  = (bf16_t*)alloc((size_t)L_ * DFF_ * D_ * 2);
    bf16_t* wprT  = (bf16_t*)alloc((size_t)L_ * D_ * DFF_ * 2);
    bf16_t* qkvb  = (bf16_t*)alloc((size_t)BT_ * 3 * D_ * 2);
    bf16_t* vtbuf = (bf16_t*)alloc((size_t)B_ * H_ * DH_ * T_ * 2);
    bf16_t* yb    = (bf16_t*)alloc((size_t)BT_ * D_ * 2);
    bf16_t* hab   = (bf16_t*)alloc((size_t)BT_ * D_ * 2);
    bf16_t* fcb   = (bf16_t*)alloc((size_t)BT_ * DFF_ * 2);
    float*  xb    = (float*) alloc((size_t)BT_ * D_ * 4);

    bf16_t* hfin = (bf16_t*)d_ws;
    size_t hbytes = ((size_t)BT_ * D_ * 2 + 255) & ~(size_t)255;
    bool wte_ws = ws_size >= hbytes + (size_t)V_ * D_ * 2 + 256;
    bf16_t* wteb = wte_ws ? (bf16_t*)((char*)d_ws + hbytes) : nullptr;

    if (wte_ws)
        conv_kernel<<<(V_ * D_ / 4 + 255) / 256, 256, 0, stream>>>(wte, wteb, V_ * D_ / 4);
    tconv_kernel<<<dim3(3 * D_ / 32, D_ / 32, L_), 256, 0, stream>>>(w_qkv, wqkvT, D_, 3 * D_);
    tconv_kernel<<<dim3(D_ / 32, D_ / 32, L_), 256, 0, stream>>>(w_ao, waoT, D_, D_);
    tconv_kernel<<<dim3(DFF_ / 32, D_ / 32, L_), 256, 0, stream>>>(w_fc, wfcT, D_, DFF_);
    tconv_kernel<<<dim3(D_ / 32, DFF_ / 32, L_), 256, 0, stream>>>(w_pr, wprT, DFF_, D_);

    embed_ln_kernel<<<BT_, 128, 0, stream>>>(idx, wte, wpe, ln1_g, ln1_b, xb, hab);

    for (int l = 0; l < L_; ++l) {
        // qkv: 128^2 tile -> 768 blocks (~3/CU); mm8's 192 left 64 CUs idle
        mm_kernel<64, 0, true, false, false><<<(3 * D_ / 128) * (BT_ / 128), 256, 0, stream>>>(
            hab, wqkvT + (size_t)l * 3 * D_ * D_, nullptr, b_qkv + (size_t)l * 3 * D_,
            nullptr, qkvb, BT_, 3 * D_, D_);
        vtrans_kernel<<<dim3(T_ / 32, DH_ / 32, B_ * H_), 256, 0, stream>>>(qkvb, vtbuf);
        flash_kernel<<<512, 512, 0, stream>>>(qkvb, vtbuf, yb);
        mm_ln_kernel<<<BT_ / 32, 512, 0, stream>>>(
            yb, waoT + (size_t)l * D_ * D_, b_ao + (size_t)l * D_,
            xb, ln2_g + (size_t)l * D_, ln2_b + (size_t)l * D_, hab, BT_, D_);
        mm8_kernel<1, true><<<(BT_ / 256) * (DFF_ / 256), 512, 0, stream>>>(
            hab, wfcT + (size_t)l * DFF_ * D_, b_fc + (size_t)l * DFF_,
            fcb, BT_, DFF_, D_);
        if (l < L_ - 1)
            mm_ln_kernel<<<BT_ / 32, 512, 0, stream>>>(
                fcb, wprT + (size_t)l * D_ * DFF_, b_pr + (size_t)l * D_,
                xb, ln1_g + (size_t)(l + 1) * D_, ln1_b + (size_t)(l + 1) * D_,
                hab, BT_, DFF_);
        else
            mm_ln_kernel<<<BT_ / 32, 512, 0, stream>>>(
                fcb, wprT + (size_t)l * D_ * DFF_, b_pr + (size_t)l * D_,
                xb, lnf_g, lnf_b, hfin, BT_, DFF_);
    }

    // head: 128^2 tile -> 16000 blocks, ~4 blocks/CU; short-K (8 steps) +
    // 1.05GB write stream => inter-block overlap beats the 256^2 pipeline
    if (wte_ws)
        mm_kernel<64, 0, false, false, false><<<(V_ / 128) * (BT_ / 128), 256, 0, stream>>>(
            hfin, wteb, nullptr, nullptr, nullptr, outf, BT_, V_, D_);
    else
        mm_kernel<64, 0, false, false, true><<<(V_ / 128) * (BT_ / 128), 256, 0, stream>>>(
            hfin, nullptr, wte, nullptr, nullptr, outf, BT_, V_, D_);
}

// Round 12
// 1646.702 us; speedup vs baseline: 1.0226x; 1.0226x over previous
//
#include <hip/hip_runtime.h>
#include <hip/hip_bf16.h>
#include <math.h>

#define V_   32000
#define D_   512
#define L_   6
#define H_   8
#define DH_  64
#define DFF_ 2048
#define B_   8
#define T_   1024
#define BT_  (B_*T_)

typedef __attribute__((ext_vector_type(4))) float f32x4;
typedef __attribute__((ext_vector_type(8))) short short8;
using bf16_t = __hip_bfloat16;

__device__ __forceinline__ float b2f(unsigned short u) {
    union { unsigned int i; float f; } v; v.i = ((unsigned int)u) << 16; return v.f;
}
__device__ __forceinline__ unsigned short f2b(float f) {
    bf16_t h = __float2bfloat16(f);
    return *reinterpret_cast<unsigned short*>(&h);
}
__device__ __forceinline__ void gl16(const void* g, void* l) {
    __builtin_amdgcn_global_load_lds((const __attribute__((address_space(1))) void*)g,
                                     (__attribute__((address_space(3))) void*)l, 16, 0, 0);
}
__device__ __forceinline__ float gelu_exact(float v) {
    return 0.5f * v * (1.0f + erff(v * 0.70710678118654752f));
}

// -------- fused embedding + LN1(layer0): x = wte[idx]+wpe, h = LN(x) -------
__global__ __launch_bounds__(128) void embed_ln_kernel(
        const int* __restrict__ idx, const float* __restrict__ wte,
        const float* __restrict__ wpe, const float* __restrict__ g,
        const float* __restrict__ bb, float* __restrict__ x,
        bf16_t* __restrict__ hout) {
    int bt = blockIdx.x;
    int tt = bt & (T_ - 1);
    int tok = idx[bt];
    int i = threadIdx.x;
    float4 a = ((const float4*)(wte + (size_t)tok * D_))[i];
    float4 p = ((const float4*)(wpe + (size_t)tt * D_))[i];
    float4 v = make_float4(a.x + p.x, a.y + p.y, a.z + p.z, a.w + p.w);
    ((float4*)(x + (size_t)bt * D_))[i] = v;

    float s  = v.x + v.y + v.z + v.w;
    float sq = v.x*v.x + v.y*v.y + v.z*v.z + v.w*v.w;
    #pragma unroll
    for (int o = 32; o > 0; o >>= 1) {
        s  += __shfl_down(s,  o);
        sq += __shfl_down(sq, o);
    }
    __shared__ float ss[2], ssq[2];
    if ((i & 63) == 0) { ss[i >> 6] = s; ssq[i >> 6] = sq; }
    __syncthreads();
    float mean = (ss[0] + ss[1]) * (1.0f / D_);
    float var  = (ssq[0] + ssq[1]) * (1.0f / D_) - mean * mean;
    float rstd = rsqrtf(var + 1e-5f);
    float4 gg = ((const float4*)g)[i];
    float4 b2 = ((const float4*)bb)[i];
    ushort4 o4;
    o4.x = f2b((v.x - mean) * rstd * gg.x + b2.x);
    o4.y = f2b((v.y - mean) * rstd * gg.y + b2.y);
    o4.z = f2b((v.z - mean) * rstd * gg.z + b2.z);
    o4.w = f2b((v.w - mean) * rstd * gg.w + b2.w);
    ((ushort4*)(hout + (size_t)bt * D_))[i] = o4;
}

// ---------------- fp32 -> bf16 convert (no transpose) ----------------
__global__ __launch_bounds__(256) void conv_kernel(
        const float* __restrict__ s, bf16_t* __restrict__ d, int n4) {
    int i = blockIdx.x * 256 + threadIdx.x;
    if (i >= n4) return;
    float4 f = ((const float4*)s)[i];
    ushort4 u = make_ushort4(f2b(f.x), f2b(f.y), f2b(f.z), f2b(f.w));
    ((ushort4*)d)[i] = u;
}

// ------------- fp32 [K][N] -> bf16 [N][K] transpose-convert, z = layer -----
__global__ __launch_bounds__(256) void tconv_kernel(
        const float* __restrict__ src, bf16_t* __restrict__ dst, int K, int N) {
    size_t ls = (size_t)K * N;
    const float* s = src + blockIdx.z * ls;
    bf16_t* d = dst + blockIdx.z * ls;
    __shared__ float tile[32][33];
    int n0 = blockIdx.x * 32, k0 = blockIdx.y * 32;
    int c = threadIdx.x & 31, r8 = threadIdx.x >> 5;
    #pragma unroll
    for (int i = 0; i < 4; ++i) {
        int r = r8 + i * 8;
        tile[r][c] = s[(size_t)(k0 + r) * N + n0 + c];
    }
    __syncthreads();
    #pragma unroll
    for (int i = 0; i < 4; ++i) {
        int r = r8 + i * 8;
        d[(size_t)(n0 + r) * K + k0 + c] = __float2bfloat16(tile[c][r]);
    }
}

// ----- V transpose: qkvb [BT][3D] V-part -> vt [(b*H+h)*DH + d][T] bf16 ----
__global__ __launch_bounds__(256) void vtrans_kernel(
        const bf16_t* __restrict__ qkv, bf16_t* __restrict__ vt) {
    const unsigned short* q = (const unsigned short*)qkv;
    unsigned short* d = (unsigned short*)vt;
    __shared__ unsigned short tile[32][33];
    int bh = blockIdx.z;                 // b*8+h
    int b  = bh >> 3, h = bh & 7;
    int t0 = blockIdx.x * 32, d0 = blockIdx.y * 32;
    int c = threadIdx.x & 31, r8 = threadIdx.x >> 5;
    #pragma unroll
    for (int i = 0; i < 4; ++i) {
        int r = r8 + i * 8;   // t index in tile
        tile[r][c] = q[(size_t)(b * T_ + t0 + r) * (3 * D_) + 2 * D_ + h * DH_ + d0 + c];
    }
    __syncthreads();
    #pragma unroll
    for (int i = 0; i < 4; ++i) {
        int r = r8 + i * 8;   // d index in tile
        d[(size_t)(bh * DH_ + d0 + r) * T_ + t0 + c] = tile[c][r];
    }
}

// ------------- bf16 MFMA GEMM (128x128, templated BK, swizzled) -----------
// (small-ws fallback head path only)
template<int BK, int ACT, bool OBF, bool RES, bool CONVB>
__global__ __launch_bounds__(256) void mm_kernel(
        const bf16_t* __restrict__ A,
        const bf16_t* __restrict__ Bt,
        const float*  __restrict__ Bf,
        const float*  __restrict__ bias,
        const float*  __restrict__ res,
        void* __restrict__ Cout,
        int M, int N, int K)
{
    constexpr int SLOTS = BK / 8;
    constexpr int CH    = BK / 16;
    __shared__ __align__(16) unsigned short As[128 * BK];
    __shared__ __align__(16) unsigned short Bs[128 * BK];
    const int nwg = gridDim.x;
    const int orig = blockIdx.x;
    const int q8 = nwg >> 3, r8 = nwg & 7;
    const int xcd = orig & 7, lin = orig >> 3;
    const int wg = (xcd < r8) ? xcd * (q8 + 1) + lin
                              : r8 * (q8 + 1) + (xcd - r8) * q8 + lin;
    const int gym = M >> 7;
    const int by = wg % gym;
    const int bx = wg / gym;

    const int t    = threadIdx.x;
    const int row0 = by * 128;
    const int col0 = bx * 128;
    const int lane = t & 63;
    const int wid  = t >> 6;
    const int wm   = (wid & 1) * 64;
    const int wn   = (wid >> 1) * 64;
    const int fr   = lane & 15;
    const int fq   = lane >> 4;

    f32x4 acc[4][4];
    #pragma unroll
    for (int m = 0; m < 4; ++m)
        #pragma unroll
        for (int n = 0; n < 4; ++n)
            acc[m][n] = (f32x4)(0.0f);

    const unsigned short* Ab  = (const unsigned short*)A;
    const unsigned short* Btb = (const unsigned short*)Bt;

    for (int k0 = 0; k0 < K; k0 += BK) {
        __syncthreads();
        #pragma unroll
        for (int i = 0; i < CH; ++i) {
            int c = t + i * 256;
            int row = c / SLOTS;
            int sl  = (c & (SLOTS - 1)) ^ (row & 7);
            gl16(Ab + (size_t)(row0 + row) * K + k0 + sl * 8, As + (size_t)c * 8);
        }
        if (!CONVB) {
            #pragma unroll
            for (int i = 0; i < CH; ++i) {
                int c = t + i * 256;
                int row = c / SLOTS;
                int sl  = (c & (SLOTS - 1)) ^ (row & 7);
                gl16(Btb + (size_t)(col0 + row) * K + k0 + sl * 8, Bs + (size_t)c * 8);
            }
        } else {
            #pragma unroll
            for (int i = 0; i < CH; ++i) {
                int c = t + i * 256;
                int row = c / SLOTS;
                int sl  = (c & (SLOTS - 1)) ^ (row & 7);
                const float* sp = Bf + (size_t)(col0 + row) * K + k0 + sl * 8;
                float4 f0 = ((const float4*)sp)[0];
                float4 f1 = ((const float4*)sp)[1];
                short8 pk;
                pk[0] = f2b(f0.x); pk[1] = f2b(f0.y); pk[2] = f2b(f0.z); pk[3] = f2b(f0.w);
                pk[4] = f2b(f1.x); pk[5] = f2b(f1.y); pk[6] = f2b(f1.z); pk[7] = f2b(f1.w);
                *(short8*)(Bs + (size_t)c * 8) = pk;
            }
        }
        __syncthreads();

        #pragma unroll
        for (int kk = 0; kk < BK / 32; ++kk) {
            short8 av[4], bv[4];
            #pragma unroll
            for (int m = 0; m < 4; ++m) {
                int R = wm + m * 16 + fr;
                int sl = (kk * 4 + fq) ^ (fr & 7);
                av[m] = *(const short8*)(As + (size_t)R * BK + sl * 8);
            }
            #pragma unroll
            for (int n = 0; n < 4; ++n) {
                int R = wn + n * 16 + fr;
                int sl = (kk * 4 + fq) ^ (fr & 7);
                bv[n] = *(const short8*)(Bs + (size_t)R * BK + sl * 8);
            }
            #pragma unroll
            for (int m = 0; m < 4; ++m)
                #pragma unroll
                for (int n = 0; n < 4; ++n)
                    acc[m][n] = __builtin_amdgcn_mfma_f32_16x16x32_bf16(av[m], bv[n], acc[m][n], 0, 0, 0);
        }
    }

    #pragma unroll
    for (int n = 0; n < 4; ++n) {
        int col = col0 + wn + n * 16 + fr;
        float bb = bias ? bias[col] : 0.0f;
        #pragma unroll
        for (int m = 0; m < 4; ++m) {
            int rbase = row0 + wm + m * 16 + fq * 4;
            #pragma unroll
            for (int r = 0; r < 4; ++r) {
                float v = acc[m][n][r] + bb;
                if (ACT == 1) v = gelu_exact(v);
                size_t off = (size_t)(rbase + r) * N + col;
                if (RES) v += res[off];
                if (OBF) ((bf16_t*)Cout)[off] = __float2bfloat16(v);
                else     ((float*)Cout)[off]  = v;
            }
        }
    }
}

// ====== fused GEMM(32x512 tile) + bias + residual + LayerNorm (r8 v1) ======
__global__ __launch_bounds__(512) void mm_ln_kernel(
        const bf16_t* __restrict__ A,
        const bf16_t* __restrict__ Bt,     // [512][K]
        const float*  __restrict__ bias,   // [512]
        float*        __restrict__ xio,    // [M][512] residual in/out
        const float*  __restrict__ g,
        const float*  __restrict__ lb,
        bf16_t*       __restrict__ hout,   // [M][512]
        int M, int K)
{
    __shared__ __align__(16) unsigned short As[32 * 64];    // 4 KB
    __shared__ __align__(16) unsigned short Bs[512 * 64];   // 64 KB
    __shared__ float stats[32][8][2];                       // 2 KB

    const int row0 = blockIdx.x * 32;
    const int t    = threadIdx.x;
    const int lane = t & 63;
    const int w    = t >> 6;
    const int fr   = lane & 15;
    const int fq   = lane >> 4;

    const unsigned short* Ab  = (const unsigned short*)A;
    const unsigned short* Btb = (const unsigned short*)Bt;

    f32x4 acc[2][4];
    #pragma unroll
    for (int m = 0; m < 2; ++m)
        #pragma unroll
        for (int n = 0; n < 4; ++n)
            acc[m][n] = (f32x4)(0.0f);

    for (int k0 = 0; k0 < K; k0 += 64) {
        __syncthreads();
        if (t < 256) {              // A: 32 rows x 8 slots
            int c = t;
            int row = c >> 3, sl = (c & 7) ^ (row & 7);
            gl16(Ab + (size_t)(row0 + row) * K + k0 + sl * 8, As + (size_t)c * 8);
        }
        #pragma unroll
        for (int i = 0; i < 8; ++i) {   // B: 512 rows x 8 slots
            int c = t + i * 512;
            int row = c >> 3, sl = (c & 7) ^ (row & 7);
            gl16(Btb + (size_t)row * K + k0 + sl * 8, Bs + (size_t)c * 8);
        }
        __syncthreads();

        #pragma unroll
        for (int kk = 0; kk < 2; ++kk) {
            int sl = (kk * 4 + fq) ^ (fr & 7);
            short8 av[2], bv[4];
            #pragma unroll
            for (int m = 0; m < 2; ++m)
                av[m] = *(const short8*)(As + (size_t)(m * 16 + fr) * 64 + sl * 8);
            #pragma unroll
            for (int n = 0; n < 4; ++n)
                bv[n] = *(const short8*)(Bs + (size_t)(w * 64 + n * 16 + fr) * 64 + sl * 8);
            #pragma unroll
            for (int m = 0; m < 2; ++m)
                #pragma unroll
                for (int n = 0; n < 4; ++n)
                    acc[m][n] = __builtin_amdgcn_mfma_f32_16x16x32_bf16(av[m], bv[n], acc[m][n], 0, 0, 0);
        }
    }

    float vv[2][4][4];
    #pragma unroll
    for (int m = 0; m < 2; ++m) {
        #pragma unroll
        for (int r = 0; r < 4; ++r) {
            int rowl = m * 16 + fq * 4 + r;
            float ps = 0.0f, pq = 0.0f;
            #pragma unroll
            for (int n = 0; n < 4; ++n) {
                int col = w * 64 + n * 16 + fr;
                float v = acc[m][n][r] + bias[col] +
                          xio[(size_t)(row0 + rowl) * D_ + col];
                vv[m][n][r] = v;
                ps += v; pq += v * v;
            }
            ps += __shfl_xor(ps, 1); pq += __shfl_xor(pq, 1);
            ps += __shfl_xor(ps, 2); pq += __shfl_xor(pq, 2);
            ps += __shfl_xor(ps, 4); pq += __shfl_xor(pq, 4);
            ps += __shfl_xor(ps, 8); pq += __shfl_xor(pq, 8);
            if (fr == 0) { stats[rowl][w][0] = ps; stats[rowl][w][1] = pq; }
        }
    }
    __syncthreads();

    #pragma unroll
    for (int m = 0; m < 2; ++m) {
        #pragma unroll
        for (int r = 0; r < 4; ++r) {
            int rowl = m * 16 + fq * 4 + r;
            float su = 0.0f, sq = 0.0f;
            #pragma unroll
            for (int ww = 0; ww < 8; ++ww) {
                su += stats[rowl][ww][0];
                sq += stats[rowl][ww][1];
            }
            float mean = su * (1.0f / D_);
            float var  = sq * (1.0f / D_) - mean * mean;
            float rstd = rsqrtf(var + 1e-5f);
            #pragma unroll
            for (int n = 0; n < 4; ++n) {
                int col = w * 64 + n * 16 + fr;
                float v = vv[m][n][r];
                size_t off = (size_t)(row0 + rowl) * D_ + col;
                xio[off] = v;
                hout[off] = __float2bfloat16((v - mean) * rstd * g[col] + lb[col]);
            }
        }
    }
}

// ============ 256x256 8-phase pipelined bf16 GEMM (T2+T3+T4+T5) ============
// vmcnt(6): 3 half-tiles in flight. Safety (derived r12): stage order
// A0',B0',A1',B1' at phases P0..P3; compute (A0B0),(A1B0),(A0B1),(A1B1).
// At step s P0 after issue, queue<=8; vmcnt(6) drains s-1P1 (=curB0);
// curA0 drained at s-1P3. P1 drains curA1, P2 drains curB1. Per-wave vmcnt
// + following s_barrier makes it collectively safe (each wave stages its
// share of every half-tile in the same phase).
#define MM8_PHASE(MH, NH, HALF, SRCB, R0, DSTB)                               \
  {                                                                           \
    short8 af[2][4]; short8 bg[2][2];                                         \
    _Pragma("unroll")                                                         \
    for (int ks = 0; ks < 2; ++ks) {                                          \
      _Pragma("unroll")                                                       \
      for (int m = 0; m < 4; ++m) {                                           \
        int row = ((MH)*4 + m)*32 + wm*16 + fr;                               \
        int sl  = (ks*4 + fq) ^ (fr & 7);                                     \
        af[ks][m] = *(const short8*)(curA + (size_t)row*64 + (size_t)sl*8);   \
      }                                                                       \
      _Pragma("unroll")                                                       \
      for (int n = 0; n < 2; ++n) {                                           \
        int col = ((NH)*2 + n)*64 + wn*16 + fr;                               \
        int sl  = (ks*4 + fq) ^ (fr & 7);                                     \
        bg[ks][n] = *(const short8*)(curB + (size_t)col*64 + (size_t)sl*8);   \
      }                                                                       \
    }                                                                         \
    if (pf) {                                                                 \
      _Pragma("unroll")                                                       \
      for (int i = 0; i < 2; ++i) {                                           \
        int c = (HALF)*1024 + i*512 + t;                                      \
        int row = c >> 3, sl = (c & 7) ^ (row & 7);                           \
        gl16(SRCB + (size_t)((R0) + row)*K + k0n + sl*8,                      \
             DSTB + (size_t)c*8);                                             \
      }                                                                       \
      asm volatile("s_waitcnt vmcnt(6)" ::: "memory");                        \
    } else if ((MH) == 0 && (NH) == 0) {                                      \
      asm volatile("s_waitcnt vmcnt(0)" ::: "memory");                        \
    }                                                                         \
    asm volatile("s_barrier" ::: "memory");                                   \
    asm volatile("s_waitcnt lgkmcnt(0)" ::: "memory");                        \
    __builtin_amdgcn_sched_barrier(0);                                        \
    __builtin_amdgcn_s_setprio(1);                                            \
    _Pragma("unroll")                                                         \
    for (int ks = 0; ks < 2; ++ks)                                            \
      _Pragma("unroll")                                                       \
      for (int m = 0; m < 4; ++m)                                             \
        _Pragma("unroll")                                                     \
        for (int n = 0; n < 2; ++n)                                           \
          acc[(MH)*4+m][(NH)*2+n] = __builtin_amdgcn_mfma_f32_16x16x32_bf16(  \
              af[ks][m], bg[ks][n], acc[(MH)*4+m][(NH)*2+n], 0, 0, 0);        \
    __builtin_amdgcn_s_setprio(0);                                            \
    __builtin_amdgcn_sched_barrier(0);                                        \
    asm volatile("s_barrier" ::: "memory");                                   \
  }

template<int ACT, bool OBF>
__global__ __launch_bounds__(512) void mm8_kernel(
        const bf16_t* __restrict__ A,    // [M][K] bf16
        const bf16_t* __restrict__ Bt,   // [N][K] bf16
        const float*  __restrict__ bias,
        void* __restrict__ Cout,
        int M, int N, int K)
{
    __shared__ __align__(16) unsigned short sA[2][256 * 64];
    __shared__ __align__(16) unsigned short sB[2][256 * 64];

    const int nwg = gridDim.x;
    const int orig = blockIdx.x;
    const int q8 = nwg >> 3, r8 = nwg & 7;
    const int xcd = orig & 7, lin = orig >> 3;
    const int wg = (xcd < r8) ? xcd * (q8 + 1) + lin
                              : r8 * (q8 + 1) + (xcd - r8) * q8 + lin;
    const int gym = M >> 8;
    const int by = wg % gym;
    const int bx = wg / gym;
    const int row0 = by * 256;
    const int col0 = bx * 256;

    const int t    = threadIdx.x;
    const int lane = t & 63;
    const int wid  = t >> 6;
    const int wm   = wid >> 2;
    const int wn   = wid & 3;
    const int fr   = lane & 15;
    const int fq   = lane >> 4;

    const unsigned short* Ab = (const unsigned short*)A;
    const unsigned short* Bb = (const unsigned short*)Bt;

    f32x4 acc[8][4];
    #pragma unroll
    for (int m = 0; m < 8; ++m)
        #pragma unroll
        for (int n = 0; n < 4; ++n)
            acc[m][n] = (f32x4)(0.0f);

    const int NK = K >> 6;

    #pragma unroll
    for (int h = 0; h < 2; ++h)
        #pragma unroll
        for (int i = 0; i < 2; ++i) {
            int c = h * 1024 + i * 512 + t;
            int row = c >> 3, sl = (c & 7) ^ (row & 7);
            gl16(Ab + (size_t)(row0 + row) * K + sl * 8, &sA[0][(size_t)c * 8]);
            gl16(Bb + (size_t)(col0 + row) * K + sl * 8, &sB[0][(size_t)c * 8]);
        }
    asm volatile("s_waitcnt vmcnt(0)" ::: "memory");
    asm volatile("s_barrier" ::: "memory");

    for (int s = 0; s < NK; ++s) {
        const unsigned short* curA = sA[s & 1];
        const unsigned short* curB = sB[s & 1];
        unsigned short* nxA = (unsigned short*)sA[(s + 1) & 1];
        unsigned short* nxB = (unsigned short*)sB[(s + 1) & 1];
        const int k0n = (s + 1) << 6;
        const bool pf = (s + 1) < NK;
        MM8_PHASE(0, 0, 0, Ab, row0, nxA)
        MM8_PHASE(1, 0, 0, Bb, col0, nxB)
        MM8_PHASE(0, 1, 1, Ab, row0, nxA)
        MM8_PHASE(1, 1, 1, Bb, col0, nxB)
    }

    #pragma unroll
    for (int n = 0; n < 4; ++n) {
        int col = col0 + n * 64 + wn * 16 + fr;
        float bb = bias ? bias[col] : 0.0f;
        #pragma unroll
        for (int m = 0; m < 8; ++m) {
            int rbase = row0 + m * 32 + wm * 16 + fq * 4;
            #pragma unroll
            for (int r = 0; r < 4; ++r) {
                float v = acc[m][n][r] + bb;
                if (ACT == 1) v = gelu_exact(v);
                size_t off = (size_t)(rbase + r) * N + col;
                if (OBF) ((bf16_t*)Cout)[off] = __float2bfloat16(v);
                else     ((float*)Cout)[off]  = v;
            }
        }
    }
}

// ---- MFMA flash attention: gl16-staged K/V (pre-swizzled src), dbuf -------
__global__ __launch_bounds__(512, 2) void flash_kernel(
        const bf16_t* __restrict__ qkv, const bf16_t* __restrict__ vt,
        bf16_t* __restrict__ y)
{
    __shared__ __align__(16) unsigned short Ks[2][64 * 64];  // [j][d] 8KB x2
    __shared__ __align__(16) unsigned short Vs[2][64 * 64];  // [d][j] 8KB x2
    __shared__ __align__(16) unsigned short Pls[128][72];    // 18.4KB

    const int qt = (T_ / 128 - 1) - (blockIdx.x >> 6);
    const int bh = blockIdx.x & 63;
    const int h  = bh & (H_ - 1);
    const int b  = bh >> 3;
    const int t  = threadIdx.x;
    const int lane = t & 63;
    const int w    = t >> 6;
    const int fr   = lane & 15;
    const int fq   = lane >> 4;
    const int srow = t >> 3;                 // staging row (0..63)
    const int ssl  = (t & 7) ^ (srow & 7);   // pre-swizzled source slot

    const unsigned short* qkvb = (const unsigned short*)qkv;
    const unsigned short* vtb  = (const unsigned short*)vt;

    short8 avq[2];
    {
        const unsigned short* qrow = qkvb +
            (size_t)(b * T_ + qt * 128 + w * 16 + fr) * (3 * D_) + h * DH_;
        avq[0] = *(const short8*)(qrow + fq * 8);
        avq[1] = *(const short8*)(qrow + 32 + fq * 8);
    }

    float mi[4], li[4];
    f32x4 oacc[4];
    #pragma unroll
    for (int r = 0; r < 4; ++r) { mi[r] = -INFINITY; li[r] = 0.0f; }
    #pragma unroll
    for (int d = 0; d < 4; ++d) oacc[d] = (f32x4)(0.0f);

    const int nt = 2 * qt + 2;

    gl16(qkvb + (size_t)(b * T_ + srow) * (3 * D_) + D_ + h * DH_ + ssl * 8,
         &Ks[0][(size_t)t * 8]);
    gl16(vtb + (size_t)(bh * DH_ + srow) * T_ + ssl * 8,
         &Vs[0][(size_t)t * 8]);
    __syncthreads();

    for (int jt = 0; jt < nt; ++jt) {
        const int cur = jt & 1;
        if (jt + 1 < nt) {   // async-stage next tile into buf^1
            gl16(qkvb + (size_t)(b * T_ + (jt + 1) * 64 + srow) * (3 * D_)
                     + D_ + h * DH_ + ssl * 8,
                 &Ks[cur ^ 1][(size_t)t * 8]);
            gl16(vtb + (size_t)(bh * DH_ + srow) * T_ + (jt + 1) * 64 + ssl * 8,
                 &Vs[cur ^ 1][(size_t)t * 8]);
        }

        f32x4 s[4];
        #pragma unroll
        for (int jb = 0; jb < 4; ++jb) s[jb] = (f32x4)(0.0f);
        #pragma unroll
        for (int ks = 0; ks < 2; ++ks) {
            int sl = (ks * 4 + fq) ^ (fr & 7);
            #pragma unroll
            for (int jb = 0; jb < 4; ++jb) {
                short8 bv = *(const short8*)(&Ks[cur][(size_t)(jb * 16 + fr) * 64 + sl * 8]);
                s[jb] = __builtin_amdgcn_mfma_f32_16x16x32_bf16(avq[ks], bv, s[jb], 0, 0, 0);
            }
        }

        float sv[4][4];
        const int qgb = qt * 128 + w * 16 + fq * 4;
        #pragma unroll
        for (int jb = 0; jb < 4; ++jb) {
            int jg = jt * 64 + jb * 16 + fr;
            #pragma unroll
            for (int r = 0; r < 4; ++r) {
                float x = s[jb][r] * 0.125f;
                sv[jb][r] = (jg > qgb + r) ? -INFINITY : x;
            }
        }

        #pragma unroll
        for (int r = 0; r < 4; ++r) {
            float tm = fmaxf(fmaxf(sv[0][r], sv[1][r]), fmaxf(sv[2][r], sv[3][r]));
            tm = fmaxf(tm, __shfl_xor(tm, 1));
            tm = fmaxf(tm, __shfl_xor(tm, 2));
            tm = fmaxf(tm, __shfl_xor(tm, 4));
            tm = fmaxf(tm, __shfl_xor(tm, 8));
            float mnew = fmaxf(mi[r], tm);
            float corr = __expf(mi[r] - mnew);
            float tsum = 0.0f;
            #pragma unroll
            for (int jb = 0; jb < 4; ++jb) {
                float p = __expf(sv[jb][r] - mnew);
                sv[jb][r] = p;
                tsum += p;
            }
            tsum += __shfl_xor(tsum, 1);
            tsum += __shfl_xor(tsum, 2);
            tsum += __shfl_xor(tsum, 4);
            tsum += __shfl_xor(tsum, 8);
            li[r] = li[r] * corr + tsum;
            mi[r] = mnew;
            #pragma unroll
            for (int db = 0; db < 4; ++db) oacc[db][r] *= corr;
        }

        #pragma unroll
        for (int jb = 0; jb < 4; ++jb)
            #pragma unroll
            for (int r = 0; r < 4; ++r)
                Pls[w * 16 + fq * 4 + r][jb * 16 + fr] = f2b(sv[jb][r]);

        #pragma unroll
        for (int ks = 0; ks < 2; ++ks) {
            short8 ap = *(const short8*)(&Pls[w * 16 + fr][ks * 32 + fq * 8]);
            int sl = (ks * 4 + fq) ^ (fr & 7);
            #pragma unroll
            for (int db = 0; db < 4; ++db) {
                short8 bv = *(const short8*)(&Vs[cur][(size_t)(db * 16 + fr) * 64 + sl * 8]);
                oacc[db] = __builtin_amdgcn_mfma_f32_16x16x32_bf16(ap, bv, oacc[db], 0, 0, 0);
            }
        }

        __syncthreads();  // implicit vmcnt(0)+lgkmcnt(0): prefetch landed
    }

    unsigned short* yb = (unsigned short*)y;
    #pragma unroll
    for (int r = 0; r < 4; ++r) {
        float inv = 1.0f / li[r];
        size_t row = (size_t)(b * T_ + qt * 128 + w * 16 + fq * 4 + r);
        #pragma unroll
        for (int db = 0; db < 4; ++db)
            yb[row * D_ + h * DH_ + db * 16 + fr] = f2b(oacc[db][r] * inv);
    }
}

// ---------------- launcher ----------------
extern "C" void kernel_launch(void* const* d_in, const int* in_sizes, int n_in,
                              void* d_out, int out_size, void* d_ws, size_t ws_size,
                              hipStream_t stream) {
    const int*   idx   = (const int*)  d_in[0];
    const float* wte   = (const float*)d_in[1];
    const float* wpe   = (const float*)d_in[2];
    const float* ln1_g = (const float*)d_in[3];
    const float* ln1_b = (const float*)d_in[4];
    const float* w_qkv = (const float*)d_in[5];
    const float* b_qkv = (const float*)d_in[6];
    const float* w_ao  = (const float*)d_in[7];
    const float* b_ao  = (const float*)d_in[8];
    const float* ln2_g = (const float*)d_in[9];
    const float* ln2_b = (const float*)d_in[10];
    const float* w_fc  = (const float*)d_in[11];
    const float* b_fc  = (const float*)d_in[12];
    const float* w_pr  = (const float*)d_in[13];
    const float* b_pr  = (const float*)d_in[14];
    const float* lnf_g = (const float*)d_in[15];
    const float* lnf_b = (const float*)d_in[16];
    float* outf = (float*)d_out;

    char* base = (char*)d_out;
    size_t off = 0;
    auto alloc = [&](size_t bytes) {
        void* p = base + off;
        off += (bytes + 255) & ~(size_t)255;
        return p;
    };
    bf16_t* wqkvT = (bf16_t*)alloc((size_t)L_ * 3 * D_ * D_ * 2);
    bf16_t* waoT  = (bf16_t*)alloc((size_t)L_ * D_ * D_ * 2);
    bf16_t* wfcT  = (bf16_t*)alloc((size_t)L_ * DFF_ * D_ * 2);
    bf16_t* wprT  = (bf16_t*)alloc((size_t)L_ * D_ * DFF_ * 2);
    bf16_t* qkvb  = (bf16_t*)alloc((size_t)BT_ * 3 * D_ * 2);
    bf16_t* vtbuf = (bf16_t*)alloc((size_t)B_ * H_ * DH_ * T_ * 2);
    bf16_t* yb    = (bf16_t*)alloc((size_t)BT_ * D_ * 2);
    bf16_t* hab   = (bf16_t*)alloc((size_t)BT_ * D_ * 2);
    bf16_t* fcb   = (bf16_t*)alloc((size_t)BT_ * DFF_ * 2);
    float*  xb    = (float*) alloc((size_t)BT_ * D_ * 4);

    bf16_t* hfin = (bf16_t*)d_ws;
    size_t hbytes = ((size_t)BT_ * D_ * 2 + 255) & ~(size_t)255;
    bool wte_ws = ws_size >= hbytes + (size_t)V_ * D_ * 2 + 256;
    bf16_t* wteb = wte_ws ? (bf16_t*)((char*)d_ws + hbytes) : nullptr;

    if (wte_ws)
        conv_kernel<<<(V_ * D_ / 4 + 255) / 256, 256, 0, stream>>>(wte, wteb, V_ * D_ / 4);
    tconv_kernel<<<dim3(3 * D_ / 32, D_ / 32, L_), 256, 0, stream>>>(w_qkv, wqkvT, D_, 3 * D_);
    tconv_kernel<<<dim3(D_ / 32, D_ / 32, L_), 256, 0, stream>>>(w_ao, waoT, D_, D_);
    tconv_kernel<<<dim3(DFF_ / 32, D_ / 32, L_), 256, 0, stream>>>(w_fc, wfcT, D_, DFF_);
    tconv_kernel<<<dim3(D_ / 32, DFF_ / 32, L_), 256, 0, stream>>>(w_pr, wprT, DFF_, D_);

    embed_ln_kernel<<<BT_, 128, 0, stream>>>(idx, wte, wpe, ln1_g, ln1_b, xb, hab);

    for (int l = 0; l < L_; ++l) {
        mm8_kernel<0, true><<<(BT_ / 256) * (3 * D_ / 256), 512, 0, stream>>>(
            hab, wqkvT + (size_t)l * 3 * D_ * D_, b_qkv + (size_t)l * 3 * D_,
            qkvb, BT_, 3 * D_, D_);
        vtrans_kernel<<<dim3(T_ / 32, DH_ / 32, B_ * H_), 256, 0, stream>>>(qkvb, vtbuf);
        flash_kernel<<<512, 512, 0, stream>>>(qkvb, vtbuf, yb);
        mm_ln_kernel<<<BT_ / 32, 512, 0, stream>>>(
            yb, waoT + (size_t)l * D_ * D_, b_ao + (size_t)l * D_,
            xb, ln2_g + (size_t)l * D_, ln2_b + (size_t)l * D_, hab, BT_, D_);
        mm8_kernel<1, true><<<(BT_ / 256) * (DFF_ / 256), 512, 0, stream>>>(
            hab, wfcT + (size_t)l * DFF_ * D_, b_fc + (size_t)l * DFF_,
            fcb, BT_, DFF_, D_);
        if (l < L_ - 1)
            mm_ln_kernel<<<BT_ / 32, 512, 0, stream>>>(
                fcb, wprT + (size_t)l * D_ * DFF_, b_pr + (size_t)l * D_,
                xb, ln1_g + (size_t)(l + 1) * D_, ln1_b + (size_t)(l + 1) * D_,
                hab, BT_, DFF_);
        else
            mm_ln_kernel<<<BT_ / 32, 512, 0, stream>>>(
                fcb, wprT + (size_t)l * D_ * DFF_, b_pr + (size_t)l * D_,
                xb, lnf_g, lnf_b, hfin, BT_, DFF_);
    }

    if (wte_ws)
        mm8_kernel<0, false><<<(BT_ / 256) * (V_ / 256), 512, 0, stream>>>(
            hfin, wteb, nullptr, outf, BT_, V_, D_);
    else
        mm_kernel<64, 0, false, false, true><<<(V_ / 128) * (BT_ / 128), 256, 0, stream>>>(
            hfin, nullptr, wte, nullptr, nullptr, outf, BT_, V_, D_);
}

// Round 14
// 1632.051 us; speedup vs baseline: 1.0317x; 1.0090x over previous
//
#include <hip/hip_runtime.h>
#include <hip/hip_bf16.h>
#include <math.h>

#define V_   32000
#define D_   512
#define L_   6
#define H_   8
#define DH_  64
#define DFF_ 2048
#define B_   8
#define T_   1024
#define BT_  (B_*T_)

typedef __attribute__((ext_vector_type(4))) float f32x4;
typedef __attribute__((ext_vector_type(8))) short short8;
using bf16_t = __hip_bfloat16;

__device__ __forceinline__ float b2f(unsigned short u) {
    union { unsigned int i; float f; } v; v.i = ((unsigned int)u) << 16; return v.f;
}
__device__ __forceinline__ unsigned short f2b(float f) {
    bf16_t h = __float2bfloat16(f);
    return *reinterpret_cast<unsigned short*>(&h);
}
__device__ __forceinline__ void gl16(const void* g, void* l) {
    __builtin_amdgcn_global_load_lds((const __attribute__((address_space(1))) void*)g,
                                     (__attribute__((address_space(3))) void*)l, 16, 0, 0);
}
__device__ __forceinline__ float gelu_exact(float v) {
    return 0.5f * v * (1.0f + erff(v * 0.70710678118654752f));
}

// -------- fused embedding + LN1(layer0): x = wte[idx]+wpe, h = LN(x) -------
__global__ __launch_bounds__(128) void embed_ln_kernel(
        const int* __restrict__ idx, const float* __restrict__ wte,
        const float* __restrict__ wpe, const float* __restrict__ g,
        const float* __restrict__ bb, float* __restrict__ x,
        bf16_t* __restrict__ hout) {
    int bt = blockIdx.x;
    int tt = bt & (T_ - 1);
    int tok = idx[bt];
    int i = threadIdx.x;
    float4 a = ((const float4*)(wte + (size_t)tok * D_))[i];
    float4 p = ((const float4*)(wpe + (size_t)tt * D_))[i];
    float4 v = make_float4(a.x + p.x, a.y + p.y, a.z + p.z, a.w + p.w);
    ((float4*)(x + (size_t)bt * D_))[i] = v;

    float s  = v.x + v.y + v.z + v.w;
    float sq = v.x*v.x + v.y*v.y + v.z*v.z + v.w*v.w;
    #pragma unroll
    for (int o = 32; o > 0; o >>= 1) {
        s  += __shfl_down(s,  o);
        sq += __shfl_down(sq, o);
    }
    __shared__ float ss[2], ssq[2];
    if ((i & 63) == 0) { ss[i >> 6] = s; ssq[i >> 6] = sq; }
    __syncthreads();
    float mean = (ss[0] + ss[1]) * (1.0f / D_);
    float var  = (ssq[0] + ssq[1]) * (1.0f / D_) - mean * mean;
    float rstd = rsqrtf(var + 1e-5f);
    float4 gg = ((const float4*)g)[i];
    float4 b2 = ((const float4*)bb)[i];
    ushort4 o4;
    o4.x = f2b((v.x - mean) * rstd * gg.x + b2.x);
    o4.y = f2b((v.y - mean) * rstd * gg.y + b2.y);
    o4.z = f2b((v.z - mean) * rstd * gg.z + b2.z);
    o4.w = f2b((v.w - mean) * rstd * gg.w + b2.w);
    ((ushort4*)(hout + (size_t)bt * D_))[i] = o4;
}

// ---------------- fp32 -> bf16 convert (no transpose) ----------------
__global__ __launch_bounds__(256) void conv_kernel(
        const float* __restrict__ s, bf16_t* __restrict__ d, int n4) {
    int i = blockIdx.x * 256 + threadIdx.x;
    if (i >= n4) return;
    float4 f = ((const float4*)s)[i];
    ushort4 u = make_ushort4(f2b(f.x), f2b(f.y), f2b(f.z), f2b(f.w));
    ((ushort4*)d)[i] = u;
}

// ------------- fp32 [K][N] -> bf16 [N][K] transpose-convert, z = layer -----
__global__ __launch_bounds__(256) void tconv_kernel(
        const float* __restrict__ src, bf16_t* __restrict__ dst, int K, int N) {
    size_t ls = (size_t)K * N;
    const float* s = src + blockIdx.z * ls;
    bf16_t* d = dst + blockIdx.z * ls;
    __shared__ float tile[32][33];
    int n0 = blockIdx.x * 32, k0 = blockIdx.y * 32;
    int c = threadIdx.x & 31, r8 = threadIdx.x >> 5;
    #pragma unroll
    for (int i = 0; i < 4; ++i) {
        int r = r8 + i * 8;
        tile[r][c] = s[(size_t)(k0 + r) * N + n0 + c];
    }
    __syncthreads();
    #pragma unroll
    for (int i = 0; i < 4; ++i) {
        int r = r8 + i * 8;
        d[(size_t)(n0 + r) * K + k0 + c] = __float2bfloat16(tile[c][r]);
    }
}

// ----- V transpose: qkvb [BT][3D] V-part -> vt [(b*H+h)*DH + d][T] bf16 ----
__global__ __launch_bounds__(256) void vtrans_kernel(
        const bf16_t* __restrict__ qkv, bf16_t* __restrict__ vt) {
    const unsigned short* q = (const unsigned short*)qkv;
    unsigned short* d = (unsigned short*)vt;
    __shared__ unsigned short tile[32][33];
    int bh = blockIdx.z;                 // b*8+h
    int b  = bh >> 3, h = bh & 7;
    int t0 = blockIdx.x * 32, d0 = blockIdx.y * 32;
    int c = threadIdx.x & 31, r8 = threadIdx.x >> 5;
    #pragma unroll
    for (int i = 0; i < 4; ++i) {
        int r = r8 + i * 8;   // t index in tile
        tile[r][c] = q[(size_t)(b * T_ + t0 + r) * (3 * D_) + 2 * D_ + h * DH_ + d0 + c];
    }
    __syncthreads();
    #pragma unroll
    for (int i = 0; i < 4; ++i) {
        int r = r8 + i * 8;   // d index in tile
        d[(size_t)(bh * DH_ + d0 + r) * T_ + t0 + c] = tile[c][r];
    }
}

// ------------- bf16 MFMA GEMM (128x128, templated BK, swizzled) -----------
// (small-ws fallback head path only)
template<int BK, int ACT, bool OBF, bool RES, bool CONVB>
__global__ __launch_bounds__(256) void mm_kernel(
        const bf16_t* __restrict__ A,
        const bf16_t* __restrict__ Bt,
        const float*  __restrict__ Bf,
        const float*  __restrict__ bias,
        const float*  __restrict__ res,
        void* __restrict__ Cout,
        int M, int N, int K)
{
    constexpr int SLOTS = BK / 8;
    constexpr int CH    = BK / 16;
    __shared__ __align__(16) unsigned short As[128 * BK];
    __shared__ __align__(16) unsigned short Bs[128 * BK];
    const int nwg = gridDim.x;
    const int orig = blockIdx.x;
    const int q8 = nwg >> 3, r8 = nwg & 7;
    const int xcd = orig & 7, lin = orig >> 3;
    const int wg = (xcd < r8) ? xcd * (q8 + 1) + lin
                              : r8 * (q8 + 1) + (xcd - r8) * q8 + lin;
    const int gym = M >> 7;
    const int by = wg % gym;
    const int bx = wg / gym;

    const int t    = threadIdx.x;
    const int row0 = by * 128;
    const int col0 = bx * 128;
    const int lane = t & 63;
    const int wid  = t >> 6;
    const int wm   = (wid & 1) * 64;
    const int wn   = (wid >> 1) * 64;
    const int fr   = lane & 15;
    const int fq   = lane >> 4;

    f32x4 acc[4][4];
    #pragma unroll
    for (int m = 0; m < 4; ++m)
        #pragma unroll
        for (int n = 0; n < 4; ++n)
            acc[m][n] = (f32x4)(0.0f);

    const unsigned short* Ab  = (const unsigned short*)A;
    const unsigned short* Btb = (const unsigned short*)Bt;

    for (int k0 = 0; k0 < K; k0 += BK) {
        __syncthreads();
        #pragma unroll
        for (int i = 0; i < CH; ++i) {
            int c = t + i * 256;
            int row = c / SLOTS;
            int sl  = (c & (SLOTS - 1)) ^ (row & 7);
            gl16(Ab + (size_t)(row0 + row) * K + k0 + sl * 8, As + (size_t)c * 8);
        }
        if (!CONVB) {
            #pragma unroll
            for (int i = 0; i < CH; ++i) {
                int c = t + i * 256;
                int row = c / SLOTS;
                int sl  = (c & (SLOTS - 1)) ^ (row & 7);
                gl16(Btb + (size_t)(col0 + row) * K + k0 + sl * 8, Bs + (size_t)c * 8);
            }
        } else {
            #pragma unroll
            for (int i = 0; i < CH; ++i) {
                int c = t + i * 256;
                int row = c / SLOTS;
                int sl  = (c & (SLOTS - 1)) ^ (row & 7);
                const float* sp = Bf + (size_t)(col0 + row) * K + k0 + sl * 8;
                float4 f0 = ((const float4*)sp)[0];
                float4 f1 = ((const float4*)sp)[1];
                short8 pk;
                pk[0] = f2b(f0.x); pk[1] = f2b(f0.y); pk[2] = f2b(f0.z); pk[3] = f2b(f0.w);
                pk[4] = f2b(f1.x); pk[5] = f2b(f1.y); pk[6] = f2b(f1.z); pk[7] = f2b(f1.w);
                *(short8*)(Bs + (size_t)c * 8) = pk;
            }
        }
        __syncthreads();

        #pragma unroll
        for (int kk = 0; kk < BK / 32; ++kk) {
            short8 av[4], bv[4];
            #pragma unroll
            for (int m = 0; m < 4; ++m) {
                int R = wm + m * 16 + fr;
                int sl = (kk * 4 + fq) ^ (fr & 7);
                av[m] = *(const short8*)(As + (size_t)R * BK + sl * 8);
            }
            #pragma unroll
            for (int n = 0; n < 4; ++n) {
                int R = wn + n * 16 + fr;
                int sl = (kk * 4 + fq) ^ (fr & 7);
                bv[n] = *(const short8*)(Bs + (size_t)R * BK + sl * 8);
            }
            #pragma unroll
            for (int m = 0; m < 4; ++m)
                #pragma unroll
                for (int n = 0; n < 4; ++n)
                    acc[m][n] = __builtin_amdgcn_mfma_f32_16x16x32_bf16(av[m], bv[n], acc[m][n], 0, 0, 0);
        }
    }

    #pragma unroll
    for (int n = 0; n < 4; ++n) {
        int col = col0 + wn + n * 16 + fr;
        float bb = bias ? bias[col] : 0.0f;
        #pragma unroll
        for (int m = 0; m < 4; ++m) {
            int rbase = row0 + wm + m * 16 + fq * 4;
            #pragma unroll
            for (int r = 0; r < 4; ++r) {
                float v = acc[m][n][r] + bb;
                if (ACT == 1) v = gelu_exact(v);
                size_t off = (size_t)(rbase + r) * N + col;
                if (RES) v += res[off];
                if (OBF) ((bf16_t*)Cout)[off] = __float2bfloat16(v);
                else     ((float*)Cout)[off]  = v;
            }
        }
    }
}

// ====== fused GEMM(32x512 tile) + bias + residual + LayerNorm (r8 v1) ======
__global__ __launch_bounds__(512) void mm_ln_kernel(
        const bf16_t* __restrict__ A,
        const bf16_t* __restrict__ Bt,     // [512][K]
        const float*  __restrict__ bias,   // [512]
        float*        __restrict__ xio,    // [M][512] residual in/out
        const float*  __restrict__ g,
        const float*  __restrict__ lb,
        bf16_t*       __restrict__ hout,   // [M][512]
        int M, int K)
{
    __shared__ __align__(16) unsigned short As[32 * 64];    // 4 KB
    __shared__ __align__(16) unsigned short Bs[512 * 64];   // 64 KB
    __shared__ float stats[32][8][2];                       // 2 KB

    const int row0 = blockIdx.x * 32;
    const int t    = threadIdx.x;
    const int lane = t & 63;
    const int w    = t >> 6;
    const int fr   = lane & 15;
    const int fq   = lane >> 4;

    const unsigned short* Ab  = (const unsigned short*)A;
    const unsigned short* Btb = (const unsigned short*)Bt;

    f32x4 acc[2][4];
    #pragma unroll
    for (int m = 0; m < 2; ++m)
        #pragma unroll
        for (int n = 0; n < 4; ++n)
            acc[m][n] = (f32x4)(0.0f);

    for (int k0 = 0; k0 < K; k0 += 64) {
        __syncthreads();
        if (t < 256) {              // A: 32 rows x 8 slots
            int c = t;
            int row = c >> 3, sl = (c & 7) ^ (row & 7);
            gl16(Ab + (size_t)(row0 + row) * K + k0 + sl * 8, As + (size_t)c * 8);
        }
        #pragma unroll
        for (int i = 0; i < 8; ++i) {   // B: 512 rows x 8 slots
            int c = t + i * 512;
            int row = c >> 3, sl = (c & 7) ^ (row & 7);
            gl16(Btb + (size_t)row * K + k0 + sl * 8, Bs + (size_t)c * 8);
        }
        __syncthreads();

        #pragma unroll
        for (int kk = 0; kk < 2; ++kk) {
            int sl = (kk * 4 + fq) ^ (fr & 7);
            short8 av[2], bv[4];
            #pragma unroll
            for (int m = 0; m < 2; ++m)
                av[m] = *(const short8*)(As + (size_t)(m * 16 + fr) * 64 + sl * 8);
            #pragma unroll
            for (int n = 0; n < 4; ++n)
                bv[n] = *(const short8*)(Bs + (size_t)(w * 64 + n * 16 + fr) * 64 + sl * 8);
            #pragma unroll
            for (int m = 0; m < 2; ++m)
                #pragma unroll
                for (int n = 0; n < 4; ++n)
                    acc[m][n] = __builtin_amdgcn_mfma_f32_16x16x32_bf16(av[m], bv[n], acc[m][n], 0, 0, 0);
        }
    }

    float vv[2][4][4];
    #pragma unroll
    for (int m = 0; m < 2; ++m) {
        #pragma unroll
        for (int r = 0; r < 4; ++r) {
            int rowl = m * 16 + fq * 4 + r;
            float ps = 0.0f, pq = 0.0f;
            #pragma unroll
            for (int n = 0; n < 4; ++n) {
                int col = w * 64 + n * 16 + fr;
                float v = acc[m][n][r] + bias[col] +
                          xio[(size_t)(row0 + rowl) * D_ + col];
                vv[m][n][r] = v;
                ps += v; pq += v * v;
            }
            ps += __shfl_xor(ps, 1); pq += __shfl_xor(pq, 1);
            ps += __shfl_xor(ps, 2); pq += __shfl_xor(pq, 2);
            ps += __shfl_xor(ps, 4); pq += __shfl_xor(pq, 4);
            ps += __shfl_xor(ps, 8); pq += __shfl_xor(pq, 8);
            if (fr == 0) { stats[rowl][w][0] = ps; stats[rowl][w][1] = pq; }
        }
    }
    __syncthreads();

    #pragma unroll
    for (int m = 0; m < 2; ++m) {
        #pragma unroll
        for (int r = 0; r < 4; ++r) {
            int rowl = m * 16 + fq * 4 + r;
            float su = 0.0f, sq = 0.0f;
            #pragma unroll
            for (int ww = 0; ww < 8; ++ww) {
                su += stats[rowl][ww][0];
                sq += stats[rowl][ww][1];
            }
            float mean = su * (1.0f / D_);
            float var  = sq * (1.0f / D_) - mean * mean;
            float rstd = rsqrtf(var + 1e-5f);
            #pragma unroll
            for (int n = 0; n < 4; ++n) {
                int col = w * 64 + n * 16 + fr;
                float v = vv[m][n][r];
                size_t off = (size_t)(row0 + rowl) * D_ + col;
                xio[off] = v;
                hout[off] = __float2bfloat16((v - mean) * rstd * g[col] + lb[col]);
            }
        }
    }
}

// ============ 256x256 8-phase pipelined bf16 GEMM (T2+T3+T4+T5) ============
// vmcnt(6): 3 half-tiles in flight (safety derivation in r12 notes).
#define MM8_PHASE(MH, NH, HALF, SRCB, R0, DSTB)                               \
  {                                                                           \
    short8 af[2][4]; short8 bg[2][2];                                         \
    _Pragma("unroll")                                                         \
    for (int ks = 0; ks < 2; ++ks) {                                          \
      _Pragma("unroll")                                                       \
      for (int m = 0; m < 4; ++m) {                                           \
        int row = ((MH)*4 + m)*32 + wm*16 + fr;                               \
        int sl  = (ks*4 + fq) ^ (fr & 7);                                     \
        af[ks][m] = *(const short8*)(curA + (size_t)row*64 + (size_t)sl*8);   \
      }                                                                       \
      _Pragma("unroll")                                                       \
      for (int n = 0; n < 2; ++n) {                                           \
        int col = ((NH)*2 + n)*64 + wn*16 + fr;                               \
        int sl  = (ks*4 + fq) ^ (fr & 7);                                     \
        bg[ks][n] = *(const short8*)(curB + (size_t)col*64 + (size_t)sl*8);   \
      }                                                                       \
    }                                                                         \
    if (pf) {                                                                 \
      _Pragma("unroll")                                                       \
      for (int i = 0; i < 2; ++i) {                                           \
        int c = (HALF)*1024 + i*512 + t;                                      \
        int row = c >> 3, sl = (c & 7) ^ (row & 7);                           \
        gl16(SRCB + (size_t)((R0) + row)*K + k0n + sl*8,                      \
             DSTB + (size_t)c*8);                                             \
      }                                                                       \
      asm volatile("s_waitcnt vmcnt(6)" ::: "memory");                        \
    } else if ((MH) == 0 && (NH) == 0) {                                      \
      asm volatile("s_waitcnt vmcnt(0)" ::: "memory");                        \
    }                                                                         \
    asm volatile("s_barrier" ::: "memory");                                   \
    asm volatile("s_waitcnt lgkmcnt(0)" ::: "memory");                        \
    __builtin_amdgcn_sched_barrier(0);                                        \
    __builtin_amdgcn_s_setprio(1);                                            \
    _Pragma("unroll")                                                         \
    for (int ks = 0; ks < 2; ++ks)                                            \
      _Pragma("unroll")                                                       \
      for (int m = 0; m < 4; ++m)                                             \
        _Pragma("unroll")                                                     \
        for (int n = 0; n < 2; ++n)                                           \
          acc[(MH)*4+m][(NH)*2+n] = __builtin_amdgcn_mfma_f32_16x16x32_bf16(  \
              af[ks][m], bg[ks][n], acc[(MH)*4+m][(NH)*2+n], 0, 0, 0);        \
    __builtin_amdgcn_s_setprio(0);                                            \
    __builtin_amdgcn_sched_barrier(0);                                        \
    asm volatile("s_barrier" ::: "memory");                                   \
  }

template<int ACT, bool OBF>
__global__ __launch_bounds__(512) void mm8_kernel(
        const bf16_t* __restrict__ A,    // [M][K] bf16
        const bf16_t* __restrict__ Bt,   // [N][K] bf16
        const float*  __restrict__ bias,
        void* __restrict__ Cout,
        int M, int N, int K)
{
    __shared__ __align__(16) unsigned short sA[2][256 * 64];
    __shared__ __align__(16) unsigned short sB[2][256 * 64];

    const int nwg = gridDim.x;
    const int orig = blockIdx.x;
    const int q8 = nwg >> 3, r8 = nwg & 7;
    const int xcd = orig & 7, lin = orig >> 3;
    const int wg = (xcd < r8) ? xcd * (q8 + 1) + lin
                              : r8 * (q8 + 1) + (xcd - r8) * q8 + lin;
    const int gym = M >> 8;
    const int by = wg % gym;
    const int bx = wg / gym;
    const int row0 = by * 256;
    const int col0 = bx * 256;

    const int t    = threadIdx.x;
    const int lane = t & 63;
    const int wid  = t >> 6;
    const int wm   = wid >> 2;
    const int wn   = wid & 3;
    const int fr   = lane & 15;
    const int fq   = lane >> 4;

    const unsigned short* Ab = (const unsigned short*)A;
    const unsigned short* Bb = (const unsigned short*)Bt;

    f32x4 acc[8][4];
    #pragma unroll
    for (int m = 0; m < 8; ++m)
        #pragma unroll
        for (int n = 0; n < 4; ++n)
            acc[m][n] = (f32x4)(0.0f);

    const int NK = K >> 6;

    #pragma unroll
    for (int h = 0; h < 2; ++h)
        #pragma unroll
        for (int i = 0; i < 2; ++i) {
            int c = h * 1024 + i * 512 + t;
            int row = c >> 3, sl = (c & 7) ^ (row & 7);
            gl16(Ab + (size_t)(row0 + row) * K + sl * 8, &sA[0][(size_t)c * 8]);
            gl16(Bb + (size_t)(col0 + row) * K + sl * 8, &sB[0][(size_t)c * 8]);
        }
    asm volatile("s_waitcnt vmcnt(0)" ::: "memory");
    asm volatile("s_barrier" ::: "memory");

    for (int s = 0; s < NK; ++s) {
        const unsigned short* curA = sA[s & 1];
        const unsigned short* curB = sB[s & 1];
        unsigned short* nxA = (unsigned short*)sA[(s + 1) & 1];
        unsigned short* nxB = (unsigned short*)sB[(s + 1) & 1];
        const int k0n = (s + 1) << 6;
        const bool pf = (s + 1) < NK;
        MM8_PHASE(0, 0, 0, Ab, row0, nxA)
        MM8_PHASE(1, 0, 0, Bb, col0, nxB)
        MM8_PHASE(0, 1, 1, Ab, row0, nxA)
        MM8_PHASE(1, 1, 1, Bb, col0, nxB)
    }

    #pragma unroll
    for (int n = 0; n < 4; ++n) {
        int col = col0 + n * 64 + wn * 16 + fr;
        float bb = bias ? bias[col] : 0.0f;
        #pragma unroll
        for (int m = 0; m < 8; ++m) {
            int rbase = row0 + m * 32 + wm * 16 + fq * 4;
            #pragma unroll
            for (int r = 0; r < 4; ++r) {
                float v = acc[m][n][r] + bb;
                if (ACT == 1) v = gelu_exact(v);
                size_t off = (size_t)(rbase + r) * N + col;
                if (OBF) ((bf16_t*)Cout)[off] = __float2bfloat16(v);
                else     ((float*)Cout)[off]  = v;
            }
        }
    }
}

// ---- MFMA flash attention: gl16-staged K/V (pre-swizzled src), dbuf, T5 ---
__global__ __launch_bounds__(512, 2) void flash_kernel(
        const bf16_t* __restrict__ qkv, const bf16_t* __restrict__ vt,
        bf16_t* __restrict__ y)
{
    __shared__ __align__(16) unsigned short Ks[2][64 * 64];  // [j][d] 8KB x2
    __shared__ __align__(16) unsigned short Vs[2][64 * 64];  // [d][j] 8KB x2
    __shared__ __align__(16) unsigned short Pls[128][72];    // 18.4KB

    const int qt = (T_ / 128 - 1) - (blockIdx.x >> 6);
    const int bh = blockIdx.x & 63;
    const int h  = bh & (H_ - 1);
    const int b  = bh >> 3;
    const int t  = threadIdx.x;
    const int lane = t & 63;
    const int w    = t >> 6;
    const int fr   = lane & 15;
    const int fq   = lane >> 4;
    const int srow = t >> 3;                 // staging row (0..63)
    const int ssl  = (t & 7) ^ (srow & 7);   // pre-swizzled source slot

    const unsigned short* qkvb = (const unsigned short*)qkv;
    const unsigned short* vtb  = (const unsigned short*)vt;

    short8 avq[2];
    {
        const unsigned short* qrow = qkvb +
            (size_t)(b * T_ + qt * 128 + w * 16 + fr) * (3 * D_) + h * DH_;
        avq[0] = *(const short8*)(qrow + fq * 8);
        avq[1] = *(const short8*)(qrow + 32 + fq * 8);
    }

    float mi[4], li[4];
    f32x4 oacc[4];
    #pragma unroll
    for (int r = 0; r < 4; ++r) { mi[r] = -INFINITY; li[r] = 0.0f; }
    #pragma unroll
    for (int d = 0; d < 4; ++d) oacc[d] = (f32x4)(0.0f);

    const int nt = 2 * qt + 2;

    gl16(qkvb + (size_t)(b * T_ + srow) * (3 * D_) + D_ + h * DH_ + ssl * 8,
         &Ks[0][(size_t)t * 8]);
    gl16(vtb + (size_t)(bh * DH_ + srow) * T_ + ssl * 8,
         &Vs[0][(size_t)t * 8]);
    __syncthreads();

    for (int jt = 0; jt < nt; ++jt) {
        const int cur = jt & 1;
        if (jt + 1 < nt) {   // async-stage next tile into buf^1
            gl16(qkvb + (size_t)(b * T_ + (jt + 1) * 64 + srow) * (3 * D_)
                     + D_ + h * DH_ + ssl * 8,
                 &Ks[cur ^ 1][(size_t)t * 8]);
            gl16(vtb + (size_t)(bh * DH_ + srow) * T_ + (jt + 1) * 64 + ssl * 8,
                 &Vs[cur ^ 1][(size_t)t * 8]);
        }

        f32x4 s[4];
        #pragma unroll
        for (int jb = 0; jb < 4; ++jb) s[jb] = (f32x4)(0.0f);
        __builtin_amdgcn_s_setprio(1);
        #pragma unroll
        for (int ks = 0; ks < 2; ++ks) {
            int sl = (ks * 4 + fq) ^ (fr & 7);
            #pragma unroll
            for (int jb = 0; jb < 4; ++jb) {
                short8 bv = *(const short8*)(&Ks[cur][(size_t)(jb * 16 + fr) * 64 + sl * 8]);
                s[jb] = __builtin_amdgcn_mfma_f32_16x16x32_bf16(avq[ks], bv, s[jb], 0, 0, 0);
            }
        }
        __builtin_amdgcn_s_setprio(0);

        float sv[4][4];
        const int qgb = qt * 128 + w * 16 + fq * 4;
        #pragma unroll
        for (int jb = 0; jb < 4; ++jb) {
            int jg = jt * 64 + jb * 16 + fr;
            #pragma unroll
            for (int r = 0; r < 4; ++r) {
                float x = s[jb][r] * 0.125f;
                sv[jb][r] = (jg > qgb + r) ? -INFINITY : x;
            }
        }

        #pragma unroll
        for (int r = 0; r < 4; ++r) {
            float tm = fmaxf(fmaxf(sv[0][r], sv[1][r]), fmaxf(sv[2][r], sv[3][r]));
            tm = fmaxf(tm, __shfl_xor(tm, 1));
            tm = fmaxf(tm, __shfl_xor(tm, 2));
            tm = fmaxf(tm, __shfl_xor(tm, 4));
            tm = fmaxf(tm, __shfl_xor(tm, 8));
            float mnew = fmaxf(mi[r], tm);
            float corr = __expf(mi[r] - mnew);
            float tsum = 0.0f;
            #pragma unroll
            for (int jb = 0; jb < 4; ++jb) {
                float p = __expf(sv[jb][r] - mnew);
                sv[jb][r] = p;
                tsum += p;
            }
            tsum += __shfl_xor(tsum, 1);
            tsum += __shfl_xor(tsum, 2);
            tsum += __shfl_xor(tsum, 4);
            tsum += __shfl_xor(tsum, 8);
            li[r] = li[r] * corr + tsum;
            mi[r] = mnew;
            #pragma unroll
            for (int db = 0; db < 4; ++db) oacc[db][r] *= corr;
        }

        #pragma unroll
        for (int jb = 0; jb < 4; ++jb)
            #pragma unroll
            for (int r = 0; r < 4; ++r)
                Pls[w * 16 + fq * 4 + r][jb * 16 + fr] = f2b(sv[jb][r]);

        __builtin_amdgcn_s_setprio(1);
        #pragma unroll
        for (int ks = 0; ks < 2; ++ks) {
            short8 ap = *(const short8*)(&Pls[w * 16 + fr][ks * 32 + fq * 8]);
            int sl = (ks * 4 + fq) ^ (fr & 7);
            #pragma unroll
            for (int db = 0; db < 4; ++db) {
                short8 bv = *(const short8*)(&Vs[cur][(size_t)(db * 16 + fr) * 64 + sl * 8]);
                oacc[db] = __builtin_amdgcn_mfma_f32_16x16x32_bf16(ap, bv, oacc[db], 0, 0, 0);
            }
        }
        __builtin_amdgcn_s_setprio(0);

        __syncthreads();  // implicit vmcnt(0)+lgkmcnt(0): prefetch landed
    }

    unsigned short* yb = (unsigned short*)y;
    #pragma unroll
    for (int r = 0; r < 4; ++r) {
        float inv = 1.0f / li[r];
        size_t row = (size_t)(b * T_ + qt * 128 + w * 16 + fq * 4 + r);
        #pragma unroll
        for (int db = 0; db < 4; ++db)
            yb[row * D_ + h * DH_ + db * 16 + fr] = f2b(oacc[db][r] * inv);
    }
}

// ---------------- launcher ----------------
extern "C" void kernel_launch(void* const* d_in, const int* in_sizes, int n_in,
                              void* d_out, int out_size, void* d_ws, size_t ws_size,
                              hipStream_t stream) {
    const int*   idx   = (const int*)  d_in[0];
    const float* wte   = (const float*)d_in[1];
    const float* wpe   = (const float*)d_in[2];
    const float* ln1_g = (const float*)d_in[3];
    const float* ln1_b = (const float*)d_in[4];
    const float* w_qkv = (const float*)d_in[5];
    const float* b_qkv = (const float*)d_in[6];
    const float* w_ao  = (const float*)d_in[7];
    const float* b_ao  = (const float*)d_in[8];
    const float* ln2_g = (const float*)d_in[9];
    const float* ln2_b = (const float*)d_in[10];
    const float* w_fc  = (const float*)d_in[11];
    const float* b_fc  = (const float*)d_in[12];
    const float* w_pr  = (const float*)d_in[13];
    const float* b_pr  = (const float*)d_in[14];
    const float* lnf_g = (const float*)d_in[15];
    const float* lnf_b = (const float*)d_in[16];
    float* outf = (float*)d_out;

    char* base = (char*)d_out;
    size_t off = 0;
    auto alloc = [&](size_t bytes) {
        void* p = base + off;
        off += (bytes + 255) & ~(size_t)255;
        return p;
    };
    bf16_t* wqkvT = (bf16_t*)alloc((size_t)L_ * 3 * D_ * D_ * 2);
    bf16_t* waoT  = (bf16_t*)alloc((size_t)L_ * D_ * D_ * 2);
    bf16_t* wfcT  = (bf16_t*)alloc((size_t)L_ * DFF_ * D_ * 2);
    bf16_t* wprT  = (bf16_t*)alloc((size_t)L_ * D_ * DFF_ * 2);
    bf16_t* qkvb  = (bf16_t*)alloc((size_t)BT_ * 3 * D_ * 2);
    bf16_t* vtbuf = (bf16_t*)alloc((size_t)B_ * H_ * DH_ * T_ * 2);
    bf16_t* yb    = (bf16_t*)alloc((size_t)BT_ * D_ * 2);
    bf16_t* hab   = (bf16_t*)alloc((size_t)BT_ * D_ * 2);
    bf16_t* fcb   = (bf16_t*)alloc((size_t)BT_ * DFF_ * 2);
    float*  xb    = (float*) alloc((size_t)BT_ * D_ * 4);

    bf16_t* hfin = (bf16_t*)d_ws;
    size_t hbytes = ((size_t)BT_ * D_ * 2 + 255) & ~(size_t)255;
    bool wte_ws = ws_size >= hbytes + (size_t)V_ * D_ * 2 + 256;
    bf16_t* wteb = wte_ws ? (bf16_t*)((char*)d_ws + hbytes) : nullptr;

    if (wte_ws)
        conv_kernel<<<(V_ * D_ / 4 + 255) / 256, 256, 0, stream>>>(wte, wteb, V_ * D_ / 4);
    tconv_kernel<<<dim3(3 * D_ / 32, D_ / 32, L_), 256, 0, stream>>>(w_qkv, wqkvT, D_, 3 * D_);
    tconv_kernel<<<dim3(D_ / 32, D_ / 32, L_), 256, 0, stream>>>(w_ao, waoT, D_, D_);
    tconv_kernel<<<dim3(DFF_ / 32, D_ / 32, L_), 256, 0, stream>>>(w_fc, wfcT, D_, DFF_);
    tconv_kernel<<<dim3(D_ / 32, DFF_ / 32, L_), 256, 0, stream>>>(w_pr, wprT, DFF_, D_);

    embed_ln_kernel<<<BT_, 128, 0, stream>>>(idx, wte, wpe, ln1_g, ln1_b, xb, hab);

    for (int l = 0; l < L_; ++l) {
        mm8_kernel<0, true><<<(BT_ / 256) * (3 * D_ / 256), 512, 0, stream>>>(
            hab, wqkvT + (size_t)l * 3 * D_ * D_, b_qkv + (size_t)l * 3 * D_,
            qkvb, BT_, 3 * D_, D_);
        vtrans_kernel<<<dim3(T_ / 32, DH_ / 32, B_ * H_), 256, 0, stream>>>(qkvb, vtbuf);
        flash_kernel<<<512, 512, 0, stream>>>(qkvb, vtbuf, yb);
        mm_ln_kernel<<<BT_ / 32, 512, 0, stream>>>(
            yb, waoT + (size_t)l * D_ * D_, b_ao + (size_t)l * D_,
            xb, ln2_g + (size_t)l * D_, ln2_b + (size_t)l * D_, hab, BT_, D_);
        mm8_kernel<1, true><<<(BT_ / 256) * (DFF_ / 256), 512, 0, stream>>>(
            hab, wfcT + (size_t)l * DFF_ * D_, b_fc + (size_t)l * DFF_,
            fcb, BT_, DFF_, D_);
        if (l < L_ - 1)
            mm_ln_kernel<<<BT_ / 32, 512, 0, stream>>>(
                fcb, wprT + (size_t)l * D_ * DFF_, b_pr + (size_t)l * D_,
                xb, ln1_g + (size_t)(l + 1) * D_, ln1_b + (size_t)(l + 1) * D_,
                hab, BT_, DFF_);
        else
            mm_ln_kernel<<<BT_ / 32, 512, 0, stream>>>(
                fcb, wprT + (size_t)l * D_ * DFF_, b_pr + (size_t)l * D_,
                xb, lnf_g, lnf_b, hfin, BT_, DFF_);
    }

    if (wte_ws)
        mm8_kernel<0, false><<<(BT_ / 256) * (V_ / 256), 512, 0, stream>>>(
            hfin, wteb, nullptr, outf, BT_, V_, D_);
    else
        mm_kernel<64, 0, false, false, true><<<(V_ / 128) * (BT_ / 128), 256, 0, stream>>>(
            hfin, nullptr, wte, nullptr, nullptr, outf, BT_, V_, D_);
}